// Round 6
// baseline (222.299 us; speedup 1.0000x reference)
//
#include <hip/hip_runtime.h>

typedef unsigned short u16;
typedef unsigned int u32;
typedef unsigned long long u64;
typedef long long i64;
typedef __bf16 bf16x8 __attribute__((ext_vector_type(8)));
typedef u16 u16x8 __attribute__((ext_vector_type(8)));
typedef float f32x4 __attribute__((ext_vector_type(4)));
typedef float f32x16 __attribute__((ext_vector_type(16)));

#define DEV __device__ __forceinline__

// problem constants (fixed by harness)
constexpr int BB = 2, DD = 512, NN = 2048, HH = 8, DKc = 64, D2 = 1024;

// Q pre-scale: 1/sqrt(64) * log2(e)  (folded into Q so softmax uses native exp2)
constexpr float QSC = 0.125f * 1.44269504088896340736f;

// workspace byte offsets (16B aligned); NO aliasing (ws is ~268 MB)
constexpr i64 MB = 1048576;
constexpr i64 OFF_CAT = 0;          // bf16 [B][N][D2]; [0:512)=attn (combine), [512:1024)=iq^T
constexpr i64 OFF_XKT = 8 * MB;     // bf16 [B][N][D] key_t^T
constexpr i64 OFF_XVT = 12 * MB;    // bf16 [B][N][D] value^T
constexpr i64 OFF_QH  = 16 * MB;    // bf16 [B][H][N][DK] (Q pre-scaled by QSC)
constexpr i64 OFF_KH  = 20 * MB;    // bf16 [B][H][N][DK]
constexpr i64 OFF_VT  = 24 * MB;    // bf16 [B][H][DK][N], m k'-permuted within 64-blocks
constexpr i64 OFF_HT  = 28 * MB;    // bf16 [B][N][D2]
constexpr i64 OFF_OP  = 36 * MB;    // bf16 [sp=4][B][N][D] flash partials (32 MB)
constexpr i64 OFF_LP  = 68 * MB;    // f32 [sp=4][B][H][N] flash partial row-sums
constexpr i64 OFF_WQP = 69 * MB;    // bf16 512x512 row-perm o'=h*64+dk
constexpr i64 OFF_WKP = 69 * MB + 524288;
constexpr i64 OFF_WVP = 69 * MB + 1048576;
constexpr i64 OFF_WMT = 69 * MB + 1572864;  // bf16 [c'=512][o=512] Wm^T col-permuted
constexpr i64 OFF_W1A = 71 * MB;    // bf16 [1024][512] W1 cols 0:512
constexpr i64 OFF_W1C = 72 * MB;    // bf16 [1024][1024]: cols 0:512 = W1a*Wm, cols 512: = W1b
constexpr i64 OFF_W2B = 74 * MB;    // bf16 512x1024
constexpr i64 OFF_BQP = 75 * MB;    // f32 512 (permuted)
constexpr i64 OFF_BKP = 75 * MB + 2048;
constexpr i64 OFF_BVP = 75 * MB + 4096;
constexpr i64 OFF_BNA = 75 * MB + 8192;   // f32 1024 BN scale
constexpr i64 OFF_BNC = 75 * MB + 12288;  // f32 1024 BN shift (incl b1 AND W1a*bm)
constexpr i64 OFF_MSK = 76 * MB;    // mask bits permuted for flash: u32 per (b,g,mt,lane)

DEV u16 f2bf(float f) {  // round-to-nearest-even f32->bf16
  u32 u = __float_as_uint(f);
  u = u + 0x7FFFu + ((u >> 16) & 1u);
  return (u16)(u >> 16);
}

DEV float bf2f(u16 u) { return __uint_as_float(((u32)u) << 16); }

// pack two f32 -> two bf16 (truncation) in ONE v_perm_b32; lo -> low 16 bits
DEV u32 packbf(float lo, float hi) {
  return __builtin_amdgcn_perm(__float_as_uint(hi), __float_as_uint(lo), 0x07060302u);
}

DEV float fexp2(float x) {
#if __has_builtin(__builtin_amdgcn_exp2f)
  return __builtin_amdgcn_exp2f(x);
#else
  return exp2f(x);
#endif
}

DEV bf16x8 ldfrag(const u16* p) {  // 16B-aligned LDS fragment load
  bf16x8 v;
  __builtin_memcpy(&v, __builtin_assume_aligned(p, 16), 16);
  return v;
}

DEV bf16x8 ldfrag8(const u16* p) {  // 8B-aligned 16B LDS fragment load (2x b64)
  bf16x8 v;
  __builtin_memcpy(&v, __builtin_assume_aligned(p, 8), 16);
  return v;
}

DEV bf16x8 ones8() {  // bf16 1.0 x8
  u16x8 u = {0x3F80, 0x3F80, 0x3F80, 0x3F80, 0x3F80, 0x3F80, 0x3F80, 0x3F80};
  bf16x8 v;
  __builtin_memcpy(&v, &u, 16);
  return v;
}

// async global->LDS, 16B per lane; LDS dest = wave-uniform base + lane*16
DEV void gload16(const void* g, void* lds) {
  __builtin_amdgcn_global_load_lds((__attribute__((address_space(1))) void*)g,
                                   (__attribute__((address_space(3))) void*)lds, 16, 0, 0);
}

DEV f32x4 mfma16(bf16x8 a, bf16x8 b, f32x4 c) {
  return __builtin_amdgcn_mfma_f32_16x16x32_bf16(a, b, c, 0, 0, 0);
}

DEV f32x16 mfma32(bf16x8 a, bf16x8 b, f32x16 c) {
  return __builtin_amdgcn_mfma_f32_32x32x16_bf16(a, b, c, 0, 0, 0);
}

// ---------------- prep_all: weights, BN fold, mask permute-pack, input transpose ----------------
__global__ __launch_bounds__(256) void prep_all(
    const float* __restrict__ Wq, const float* __restrict__ Wk, const float* __restrict__ Wv,
    const float* __restrict__ Wm, const float* __restrict__ W1, const float* __restrict__ W2,
    const float* __restrict__ bq, const float* __restrict__ bk, const float* __restrict__ bv,
    const float* __restrict__ bm, const float* __restrict__ b1, const float* __restrict__ gamma_,
    const float* __restrict__ beta_, const float* __restrict__ rmean,
    const float* __restrict__ rvar, const int* __restrict__ mask,
    const float* __restrict__ iq, const float* __restrict__ kt, const float* __restrict__ vv,
    u16* __restrict__ wqp, u16* __restrict__ wkp, u16* __restrict__ wvp, u16* __restrict__ wmt,
    u16* __restrict__ w1a, u16* __restrict__ w1c, u16* __restrict__ w2b,
    float* __restrict__ bqp, float* __restrict__ bkp, float* __restrict__ bvp,
    float* __restrict__ bna, float* __restrict__ bnc, u32* __restrict__ mw,
    u16* __restrict__ cat, u16* __restrict__ xkt, u16* __restrict__ xvt) {
  __shared__ float tile[32][33];
  const int blk = blockIdx.x, t = threadIdx.x;
  if (blk < 768) {  // Wq/Wk/Wv row-permute: dst row o'=h*64+dk <- src row dk*8+h
    const int which = blk >> 8, lb = blk & 255;
    const float* W = which == 0 ? Wq : (which == 1 ? Wk : Wv);
    u16* dst = which == 0 ? wqp : (which == 1 ? wkp : wvp);
    for (int e = lb * 256 + t; e < 262144; e += 65536) {
      int op = e >> 9, i = e & 511;
      int dk = op & 63, h = op >> 6;
      dst[e] = f2bf(W[(dk * 8 + h) * 512 + i]);
    }
  } else if (blk < 1024) {  // wmt[c'][o] = Wm[o][dk*8+h], c'=h*64+dk
    const int lb = blk - 768;
    for (int e = lb * 256 + t; e < 262144; e += 65536) {
      int cp = e >> 9, o = e & 511;
      int dk = cp & 63, h = cp >> 6;
      wmt[e] = f2bf(Wm[o * 512 + dk * 8 + h]);
    }
  } else if (blk < 1280) {  // w1a = W1[:, 0:512]
    const int lb = blk - 1024;
    for (int e = lb * 256 + t; e < 524288; e += 65536) {
      int row = e >> 9, o = e & 511;
      w1a[e] = f2bf(W1[(i64)row * 1024 + o]);
    }
  } else if (blk < 1536) {  // w1c[:, 512:1024] = W1[:, 512:1024]
    const int lb = blk - 1280;
    for (int e = lb * 256 + t; e < 524288; e += 65536) {
      int row = e >> 9, j = e & 511;
      w1c[(i64)row * 1024 + 512 + j] = f2bf(W1[(i64)row * 1024 + 512 + j]);
    }
  } else if (blk < 1792) {  // W2
    const int lb = blk - 1536;
    for (int e = lb * 256 + t; e < 524288; e += 65536) w2b[e] = f2bf(W2[e]);
  } else if (blk < 1808) {  // BN fold incl. s_e = sum_o W1a[e][o]*bm[o]
    __shared__ float sm[4][64];
    const int base = (blk - 1792) * 64;
    const int el = t & 63, oq = t >> 6;
    const float* wrow = W1 + (i64)(base + el) * 1024 + oq * 128;
    const float* bmq = bm + oq * 128;
    float s = 0.f;
#pragma unroll 8
    for (int j = 0; j < 128; j += 4) {
      float4 x = *(const float4*)(wrow + j);
      float4 y = *(const float4*)(bmq + j);
      s += x.x * y.x + x.y * y.y + x.z * y.z + x.w * y.w;
    }
    sm[oq][el] = s;
    __syncthreads();
    if (t < 64) {
      int e = base + t;
      float a = gamma_[e] * rsqrtf(rvar[e] + 1e-5f);
      bna[e] = a;
      bnc[e] = (b1[e] - rmean[e]) * a + beta_[e] + a * (sm[0][t] + sm[1][t] + sm[2][t] + sm[3][t]);
    }
  } else if (blk == 1808) {  // permuted projection biases
    for (int e = t; e < 512; e += 256) {
      int src = (e & 63) * 8 + (e >> 6);
      bqp[e] = bq[src]; bkp[e] = bk[src]; bvp[e] = bv[src];
    }
  } else if (blk < 2833) {  // mask permute-pack: u32 per (b, g=32-row group, mt, lane)
    const int tid = (blk - 1809) * 256 + t;  // [0, 262144)
    const int l = tid & 63, mt = (tid >> 6) & 31, g = (tid >> 11) & 63, b = tid >> 17;
    const int kv0 = mt * 64 + (l & 31);
    u32 word = 0;
#pragma unroll
    for (int reg = 0; reg < 16; ++reg) {
      int r = (reg & 3) + 8 * (reg >> 2) + 4 * (l >> 5);
      const int* mp = mask + ((i64)b * NN + g * 32 + r) * NN + kv0;
      word |= (mp[0] != 0 ? (1u << (2 * reg)) : 0u) | (mp[32] != 0 ? (2u << (2 * reg)) : 0u);
    }
    mw[tid] = word;
  } else {  // transpose+convert: (B,D,N) f32 -> (B,N,D) bf16, packed u32 stores
    const int idx = blk - 2833;
    const int bx = idx & 63, by = (idx >> 6) & 15, bz = idx >> 10;
    const int tensor = bz >> 1, b = bz & 1;
    const float* src = (tensor == 0 ? iq : (tensor == 1 ? kt : vv)) + (i64)b * DD * NN;
    u16* dst; i64 ldd; int coff;
    if (tensor == 0)      { dst = cat + (i64)b * NN * D2; ldd = D2; coff = DD; }
    else if (tensor == 1) { dst = xkt + (i64)b * NN * DD; ldd = DD; coff = 0; }
    else                  { dst = xvt + (i64)b * NN * DD; ldd = DD; coff = 0; }
    const int x0 = bx * 32, y0 = by * 32;
    const int col = t & 31, rg = t >> 5;
#pragma unroll
    for (int i = 0; i < 4; ++i) {
      int row = rg + i * 8;
      tile[row][col] = src[(i64)(y0 + row) * NN + x0 + col];
    }
    __syncthreads();
    const int dp = t & 15, rbase = t >> 4;
    u32* dst32 = (u32*)dst;
    const i64 ldw = ldd >> 1;
    const int cw = (coff + y0) >> 1;
#pragma unroll
    for (int i = 0; i < 2; ++i) {
      int rr = rbase + i * 16;
      dst32[(i64)(x0 + rr) * ldw + cw + dp] = packbf(tile[2 * dp][rr], tile[2 * dp + 1][rr]);
    }
  }
}

// ---------------- shared GEMM core: (AM*32)x(AN*32) tile, BK=64, 4 waves 2x2 ----------------
template <int AM, int AN>
DEV void gemm_core(const u16* __restrict__ A, i64 lda, const u16* __restrict__ Bp, i64 ldb,
                   int K, u16* As, u16* Bs, f32x4 (&acc)[AM][AN]) {
  constexpr int BM = AM * 32, BN = AN * 32;
  const int t = threadIdx.x, w = t >> 6, l = t & 63, quad = l >> 4, l15 = l & 15;
  const int wm = (w >> 1) * AM * 16, wn = (w & 1) * AN * 16;
  for (int kk = 0; kk < K; kk += 64) {
    __syncthreads();
#pragma unroll
    for (int j = 0; j < BM / 32; ++j) {
      int ch = j * 256 + w * 64 + l, r = ch >> 3, c = ch & 7;
      gload16(A + (i64)r * lda + kk + ((c ^ (r & 7)) << 3), As + (j * 256 + w * 64) * 8);
    }
#pragma unroll
    for (int j = 0; j < BN / 32; ++j) {
      int ch = j * 256 + w * 64 + l, r = ch >> 3, c = ch & 7;
      gload16(Bp + (i64)r * ldb + kk + ((c ^ (r & 7)) << 3), Bs + (j * 256 + w * 64) * 8);
    }
    __syncthreads();
#pragma unroll
    for (int kc = 0; kc < 2; ++kc) {
      const int sw = ((kc * 4 + quad) ^ (l15 & 7)) << 3;
      bf16x8 af[AM], bfr[AN];
#pragma unroll
      for (int i = 0; i < AM; ++i) af[i] = ldfrag(&As[(wm + i * 16 + l15) * 64 + sw]);
#pragma unroll
      for (int j = 0; j < AN; ++j) bfr[j] = ldfrag(&Bs[(wn + j * 16 + l15) * 64 + sw]);
#pragma unroll
      for (int i = 0; i < AM; ++i)
#pragma unroll
        for (int j = 0; j < AN; ++j) acc[i][j] = mfma16(af[i], bfr[j], acc[i][j]);
    }
  }
}

// ---------------- fused Q/K/V projection + Wc weight-GEMM (z==6) ----------------
__global__ __launch_bounds__(256) void qkv_gemm(const u16* __restrict__ cat,
                                                const u16* __restrict__ xkt,
                                                const u16* __restrict__ xvt,
                                                const u16* __restrict__ wqp,
                                                const u16* __restrict__ wkp,
                                                const u16* __restrict__ wvp,
                                                const u16* __restrict__ w1a,
                                                const u16* __restrict__ wmt,
                                                const float* __restrict__ bqp,
                                                const float* __restrict__ bkp,
                                                const float* __restrict__ bvp,
                                                u16* __restrict__ qh, u16* __restrict__ kh,
                                                u16* __restrict__ vt, u16* __restrict__ w1c) {
  __shared__ __align__(16) u16 As[128 * 64];
  __shared__ __align__(16) u16 Bs[64 * 64];
  const int z = blockIdx.z, b = z & 1;
  const int op = (z == 6) ? 3 : (z >> 1);
  const int t = threadIdx.x, w = t >> 6, l = t & 63, quad = l >> 4, l15 = l & 15;
  const int wm = (w >> 1) * 64, wn = (w & 1) * 32;
  int mx, ny;
  const u16 *A, *Bp;
  i64 lda, ldb;
  if (op < 2) {  // Q/K: A = activations [2048][512], B = W [512][512]
    mx = blockIdx.x; ny = blockIdx.y;
    A = (op == 0 ? cat + DD : xkt);
    lda = (op == 0 ? D2 : DD);
    A += (i64)b * NN * lda + (i64)mx * 128 * lda;
    Bp = (op == 0 ? wqp : wkp) + (i64)ny * 64 * DD;
    ldb = DD;
  } else if (op == 2) {  // V: A = Wv [512][512], B = value^T [2048][512]
    int f = blockIdx.x * 8 + blockIdx.y;
    mx = f >> 5; ny = f & 31;
    A = wvp + (i64)mx * 128 * DD; lda = DD;
    Bp = xvt + (i64)b * NN * DD + (i64)ny * 64 * DD; ldb = DD;
  } else {  // Wc = W1a * wmt^T : [1024 x 512], K=512
    if (blockIdx.x >= 8) return;
    mx = blockIdx.x; ny = blockIdx.y;
    A = w1a + (i64)mx * 128 * DD; lda = DD;
    Bp = wmt + (i64)ny * 64 * DD; ldb = DD;
  }
  f32x4 acc[4][2] = {};
  gemm_core<4, 2>(A, lda, Bp, ldb, DD, As, Bs, acc);

  const int rowBase = mx * 128 + wm + quad * 4;
  const int colBase = ny * 64 + wn + l15;
  if (op < 2) {  // head scatter: col=h*64+dk -> [b][h][n][dk]; Q scaled by QSC
    const float* bias = (op == 0 ? bqp : bkp);
    const float sc = (op == 0 ? QSC : 1.f);
    u16* dst = (op == 0 ? qh : kh) + (i64)b * HH * NN * DKc;
#pragma unroll
    for (int j = 0; j < 2; ++j) {
      const int col = colBase + j * 16;
      const float cA = bias[col];
#pragma unroll
      for (int i = 0; i < 4; ++i)
#pragma unroll
        for (int r = 0; r < 4; ++r) {
          const int row = rowBase + i * 16 + r;
          dst[(i64)(col >> 6) * (NN * 64) + (i64)row * 64 + (col & 63)] =
              f2bf((acc[i][j][r] + cA) * sc);
        }
    }
  } else if (op == 2) {  // V: row bias, store [b][o'][m'], m' = 2*(m&31) + (m>>5) within 64
    u16* dst = vt + (i64)b * HH * DKc * NN;
#pragma unroll
    for (int j = 0; j < 2; ++j) {
      const int col = colBase + j * 16;
      const int colp = (col & ~63) | (((col & 31) << 1) | ((col >> 5) & 1));
#pragma unroll
      for (int i = 0; i < 4; ++i)
#pragma unroll
        for (int r = 0; r < 4; ++r) {
          const int row = rowBase + i * 16 + r;
          dst[(i64)row * NN + colp] = f2bf(acc[i][j][r] + bvp[row]);
        }
    }
  } else {  // Wc plain store -> w1c[:, 0:512]
#pragma unroll
    for (int j = 0; j < 2; ++j) {
      const int col = colBase + j * 16;
#pragma unroll
      for (int i = 0; i < 4; ++i)
#pragma unroll
        for (int r = 0; r < 4; ++r) {
          const int row = rowBase + i * 16 + r;
          w1c[(i64)row * D2 + col] = f2bf(acc[i][j][r]);
        }
    }
  }
}

// ---------------- generic gemm_bt: C[m][n] = A[m][:]·B[n][:] (+epilogue) ----------------
// SWZ==1: XCD-pin B-tiles; grid must be (8,32,2) (W2 shape).
struct GArgs {
  const u16* A; i64 lda, sAb;
  const u16* B; i64 ldb, sBb;
  void* C; i64 ldc, sCb;
  const float* p1; const float* p2;
  int K;
};

template <int MODE, int AM, int AN, int SWZ>
__global__ __launch_bounds__(256) void gemm_bt(GArgs g) {
  __shared__ __align__(16) u16 As[AM * 32 * 64];
  __shared__ __align__(16) u16 Bs[AN * 32 * 64];
  const int t = threadIdx.x, w = t >> 6, l = t & 63, quad = l >> 4, l15 = l & 15;
  const int wm = (w >> 1) * AM * 16, wn = (w & 1) * AN * 16;
  int bx = blockIdx.x, by = blockIdx.y, bz = blockIdx.z;
  if (SWZ == 1) {  // flat = bx + 8by + 256bz; pin same-by blocks to one XCD slot
    const int i = bx + (by << 3) + (bz << 8);
    const int slot = i & 7, jj = i >> 3;
    by = slot + ((jj & 3) << 3);
    const int j2 = jj >> 2;
    bx = j2 & 7;
    bz = j2 >> 3;
  }
  const u16* A = g.A + (i64)bz * g.sAb + (i64)bx * (AM * 32) * g.lda;
  const u16* Bp = g.B + (i64)bz * g.sBb + (i64)by * (AN * 32) * g.ldb;
  f32x4 acc[AM][AN] = {};
  gemm_core<AM, AN>(A, g.lda, Bp, g.ldb, g.K, As, Bs, acc);

  const int rowBase = bx * (AM * 32) + wm + quad * 4;
  const int colBase = by * (AN * 32) + wn + l15;
#pragma unroll
  for (int j = 0; j < AN; ++j) {
    const int col = colBase + j * 16;
    float cA = 0.f, cB = 0.f;
    if (MODE == 3) { cA = g.p1[col]; cB = g.p2[col]; }
#pragma unroll
    for (int i = 0; i < AM; ++i) {
#pragma unroll
      for (int r = 0; r < 4; ++r) {
        const int row = rowBase + i * 16 + r;
        float v = acc[i][j][r];
        if (MODE == 3) {  // BN+ReLU, bf16 out
          float x = v * cA + cB;
          ((u16*)g.C + (i64)bz * g.sCb)[(i64)row * g.ldc + col] = f2bf(x > 0.f ? x : 0.f);
        } else {  // MODE 4: fp32 out, row bias (W2 -> d_out)
          ((float*)g.C + (i64)bz * g.sCb)[(i64)row * g.ldc + col] = v + g.p1[row];
        }
      }
    }
  }
}

// ---------------- flash attention v6: 32x32 MFMA, KV-split-4, head-pinned XCDs ----------------
__global__ __launch_bounds__(256) void flash_attn(const u16* __restrict__ Qh,
                                                  const u16* __restrict__ Kh,
                                                  const u16* __restrict__ Vt,
                                                  const u32* __restrict__ MW2,
                                                  u16* __restrict__ Opart,
                                                  float* __restrict__ Lp) {
  __shared__ __align__(16) u16 Ks[64 * 64];
  __shared__ __align__(16) u16 Vs[64 * 64];
  __shared__ __align__(16) u16 Ps[4][32 * 68];  // per-wave [q=32][kv'=64] pitch 68
  const int t = threadIdx.x, w = t >> 6, l = t & 63, l31 = l & 31, lh = l >> 5;
  // flat-index decode pinning all blocks of head h to XCD slot h (dispatch RR over 8 XCDs)
  const int flat = blockIdx.x;
  const int h = flat & 7;
  const int j = flat >> 3;
  const int nt = j & 15, zz = j >> 4;
  const int b = zz >> 2, sp = zz & 3;
  const u16* Qb = Qh + ((i64)(b * HH + h) * NN + nt * 128 + w * 32) * 64;
  const u16* Kb = Kh + (i64)(b * HH + h) * NN * 64;
  const u16* Vb = Vt + (i64)(b * HH + h) * 64 * NN;
  const u32* MWb = MW2 + ((i64)(b * 64 + nt * 4 + w) * 32) * 64 + l;
  const bf16x8 ONE = ones8();
  // Q fragments direct from global (A-layout: m=l31, k=kc*16+lh*8+j)
  bf16x8 qf[4];
#pragma unroll
  for (int kc = 0; kc < 4; ++kc)
    __builtin_memcpy(&qf[kc], Qb + (i64)l31 * 64 + kc * 16 + lh * 8, 16);

  f32x16 oacc0 = {}, oacc1 = {}, lacc = {};
  for (int mt = sp * 8; mt < sp * 8 + 8; ++mt) {
    __syncthreads();
#pragma unroll
    for (int j2 = 0; j2 < 2; ++j2) {  // stage K,V (64x64 each, swizzled)
      int ch = j2 * 256 + t, r = ch >> 3, c = ch & 7;
      gload16(Kb + (i64)(mt * 64 + r) * 64 + ((c ^ (r & 7)) << 3), &Ks[ch * 8]);
      gload16(Vb + (i64)r * NN + mt * 64 + ((c ^ (r & 7)) << 3), &Vs[ch * 8]);
    }
    __syncthreads();
    // S = Q K^T : 32q x 64kv per wave, two 32x32 tiles
    f32x16 s0 = {}, s1 = {};
#pragma unroll
    for (int kc = 0; kc < 4; ++kc) {
      const int r1 = 32 + l31;
      bf16x8 k0 = ldfrag(&Ks[l31 * 64 + (((kc * 2 + lh) ^ (l31 & 7)) << 3)]);
      bf16x8 k1 = ldfrag(&Ks[r1 * 64 + (((kc * 2 + lh) ^ (r1 & 7)) << 3)]);
      s0 = mfma32(qf[kc], k0, s0);
      s1 = mfma32(qf[kc], k1, s1);
    }
    // p = exp2(s), masked via AND on packed bf16 pair; kv' = 2*(kv&31) + (kv>>5)
    const u32 mword = MWb[(i64)mt * 64];
#pragma unroll
    for (int reg = 0; reg < 16; ++reg) {
      const int row = (reg & 3) + 8 * (reg >> 2) + 4 * lh;
      u32 sh = mword >> (2 * reg);
      u32 m01 = ((sh & 1u) | ((sh & 2u) << 15)) * 0xFFFFu;
      u32 pv = packbf(fexp2(s0[reg]), fexp2(s1[reg])) & m01;
      *(u32*)__builtin_assume_aligned(&Ps[w][row * 68 + l31 * 2], 4) = pv;
    }
    asm volatile("" ::: "memory");
    bf16x8 pf[4];
#pragma unroll
    for (int kc = 0; kc < 4; ++kc) pf[kc] = ldfrag8(&Ps[w][l31 * 68 + kc * 16 + lh * 8]);
#pragma unroll
    for (int kc = 0; kc < 4; ++kc) lacc = mfma32(pf[kc], ONE, lacc);  // row-sums
#pragma unroll
    for (int kc = 0; kc < 4; ++kc) {
      const int r1 = 32 + l31;
      bf16x8 v0 = ldfrag(&Vs[l31 * 64 + (((kc * 2 + lh) ^ (l31 & 7)) << 3)]);
      bf16x8 v1 = ldfrag(&Vs[r1 * 64 + (((kc * 2 + lh) ^ (r1 & 7)) << 3)]);
      oacc0 = mfma32(pf[kc], v0, oacc0);
      oacc1 = mfma32(pf[kc], v1, oacc1);
    }
  }
  // epilogue: raw bf16 partials [sp][b][n][h*64+dk] + row-sum partials
  u16* Op = Opart + (i64)sp * (BB * NN * DD) + ((i64)b * NN + nt * 128 + w * 32) * DD + h * 64;
#pragma unroll
  for (int reg = 0; reg < 16; ++reg) {
    const int row = (reg & 3) + 8 * (reg >> 2) + 4 * lh;
    Op[(i64)row * DD + l31] = f2bf(oacc0[reg]);
    Op[(i64)row * DD + 32 + l31] = f2bf(oacc1[reg]);
  }
  if (l31 == 0) {
    float* Lpb = Lp + ((i64)(sp * BB + b) * HH + h) * NN + nt * 128 + w * 32;
#pragma unroll
    for (int reg = 0; reg < 16; ++reg)
      Lpb[(reg & 3) + 8 * (reg >> 2) + 4 * lh] = lacc[reg];
  }
}

// ---------------- combine split-4 partials: cat[:,0:512] = Σ O_sp / Σ l_sp (8 elems/thr) ----------------
__global__ __launch_bounds__(256) void combine(const u16* __restrict__ Opart,
                                               const float* __restrict__ Lp,
                                               u16* __restrict__ cat) {
  const int tid = blockIdx.x * 256 + threadIdx.x;  // [0, 262144)
  const int b = tid >> 17, rem = tid & 131071;
  const int n = rem >> 6, cg = rem & 63;
  const int c0 = cg << 3, h = cg >> 3;
  const i64 base = ((i64)b * NN + n) * DD + c0;
  const i64 stride = (i64)BB * NN * DD;
  float acc[8] = {};
  float lsum = 0.f;
#pragma unroll
  for (int s = 0; s < 4; ++s) {
    u16 a[8];
    __builtin_memcpy(a, __builtin_assume_aligned(Opart + s * stride + base, 16), 16);
#pragma unroll
    for (int j = 0; j < 8; ++j) acc[j] += bf2f(a[j]);
    lsum += Lp[((i64)(s * BB + b) * HH + h) * NN + n];
  }
  float rl = __builtin_amdgcn_rcpf(lsum);
  u16 o[8];
#pragma unroll
  for (int j = 0; j < 8; ++j) o[j] = f2bf(acc[j] * rl);
  __builtin_memcpy(__builtin_assume_aligned(&cat[((i64)b * NN + n) * D2 + c0], 16), o, 16);
}

extern "C" void kernel_launch(void* const* d_in, const int* in_sizes, int n_in,
                              void* d_out, int out_size, void* d_ws, size_t ws_size,
                              hipStream_t stream) {
  (void)in_sizes; (void)n_in; (void)out_size; (void)ws_size;
  const float* iq    = (const float*)d_in[0];
  const float* kt    = (const float*)d_in[1];
  const float* vv    = (const float*)d_in[2];
  const int*   mask  = (const int*)d_in[3];
  const float* Wq    = (const float*)d_in[4];
  const float* bq    = (const float*)d_in[5];
  const float* Wk    = (const float*)d_in[6];
  const float* bk    = (const float*)d_in[7];
  const float* Wv    = (const float*)d_in[8];
  const float* bv    = (const float*)d_in[9];
  const float* Wm    = (const float*)d_in[10];
  const float* bm    = (const float*)d_in[11];
  const float* W1    = (const float*)d_in[12];
  const float* b1    = (const float*)d_in[13];
  const float* gamma_= (const float*)d_in[14];
  const float* beta_ = (const float*)d_in[15];
  const float* rmean = (const float*)d_in[16];
  const float* rvar  = (const float*)d_in[17];
  const float* W2    = (const float*)d_in[18];
  const float* b2    = (const float*)d_in[19];

  char* ws = (char*)d_ws;
  u16* cat = (u16*)(ws + OFF_CAT);
  u16* xkt = (u16*)(ws + OFF_XKT);
  u16* xvt = (u16*)(ws + OFF_XVT);
  u16* qh  = (u16*)(ws + OFF_QH);
  u16* kh  = (u16*)(ws + OFF_KH);
  u16* vt  = (u16*)(ws + OFF_VT);
  u16* ht  = (u16*)(ws + OFF_HT);
  u16* opart = (u16*)(ws + OFF_OP);
  float* lp  = (float*)(ws + OFF_LP);
  u16* wqp = (u16*)(ws + OFF_WQP);
  u16* wkp = (u16*)(ws + OFF_WKP);
  u16* wvp = (u16*)(ws + OFF_WVP);
  u16* wmt = (u16*)(ws + OFF_WMT);
  u16* w1a = (u16*)(ws + OFF_W1A);
  u16* w1c = (u16*)(ws + OFF_W1C);
  u16* w2b = (u16*)(ws + OFF_W2B);
  float* bqp = (float*)(ws + OFF_BQP);
  float* bkp = (float*)(ws + OFF_BKP);
  float* bvp = (float*)(ws + OFF_BVP);
  float* bna = (float*)(ws + OFF_BNA);
  float* bnc = (float*)(ws + OFF_BNC);
  u32* mw = (u32*)(ws + OFF_MSK);

  // 1. prep (weights/BN/mask) + input transpose, one launch
  prep_all<<<8977, 256, 0, stream>>>(Wq, Wk, Wv, Wm, W1, W2, bq, bk, bv, bm, b1, gamma_, beta_,
                                     rmean, rvar, mask, iq, kt, vv, wqp, wkp, wvp, wmt, w1a, w1c,
                                     w2b, bqp, bkp, bvp, bna, bnc, mw, cat, xkt, xvt);
  // 2. fused Q/K/V projections + Wc weight-GEMM (z==6)
  qkv_gemm<<<dim3(16, 8, 7), 256, 0, stream>>>(cat, xkt, xvt, wqp, wkp, wvp, w1a, wmt,
                                               bqp, bkp, bvp, qh, kh, vt, w1c);
  // 3. flash, 32x32 MFMA, KV-split-4, head-pinned XCD dispatch: 1024 blocks flat
  flash_attn<<<1024, 256, 0, stream>>>(qh, kh, vt, mw, opart, lp);
  // 4. combine partials into cat[:, 0:512]
  combine<<<1024, 256, 0, stream>>>(opart, lp, cat);
  // 5. W1' + BN + ReLU, batch-merged M=4096, 128x64 tiles (A-tiles XCD-pinned via gx=32)
  GArgs wa{cat, D2, 0, w1c, D2, 0, ht, D2, 0, bna, bnc, D2};
  gemm_bt<3, 4, 2, 0><<<dim3(32, 16, 1), 256, 0, stream>>>(wa);
  // 6. W2 -> d_out (fp32), B-tiles XCD-pinned via SWZ
  GArgs w2a{w2b, D2, 0, ht, D2, (i64)NN * D2, d_out, NN, (i64)DD * NN, b2, nullptr, D2};
  gemm_bt<4, 2, 2, 1><<<dim3(8, 32, 2), 256, 0, stream>>>(w2a);
}

// Round 7
// 220.932 us; speedup vs baseline: 1.0062x; 1.0062x over previous
//
#include <hip/hip_runtime.h>

typedef unsigned short u16;
typedef unsigned int u32;
typedef unsigned long long u64;
typedef long long i64;
typedef __bf16 bf16x8 __attribute__((ext_vector_type(8)));
typedef u16 u16x8 __attribute__((ext_vector_type(8)));
typedef float f32x4 __attribute__((ext_vector_type(4)));
typedef float f32x16 __attribute__((ext_vector_type(16)));

#define DEV __device__ __forceinline__

// problem constants (fixed by harness)
constexpr int BB = 2, DD = 512, NN = 2048, HH = 8, DKc = 64, D2 = 1024;

// Q pre-scale: 1/sqrt(64) * log2(e)  (folded into Q so softmax uses native exp2)
constexpr float QSC = 0.125f * 1.44269504088896340736f;

// workspace byte offsets (16B aligned); NO aliasing (ws is ~268 MB)
constexpr i64 MB = 1048576;
constexpr i64 OFF_CAT = 0;          // bf16 [B][N][D2]; [0:512)=attn (combine), [512:1024)=iq^T
constexpr i64 OFF_XKT = 8 * MB;     // bf16 [B][N][D] key_t^T
constexpr i64 OFF_XVT = 12 * MB;    // bf16 [B][N][D] value^T
constexpr i64 OFF_QH  = 16 * MB;    // bf16 [B][H][N][DK] (Q pre-scaled by QSC)
constexpr i64 OFF_KH  = 20 * MB;    // bf16 [B][H][N][DK]
constexpr i64 OFF_VT  = 24 * MB;    // bf16 [B][H][DK][N]  (natural m)
constexpr i64 OFF_HT  = 28 * MB;    // bf16 [B][N][D2]
constexpr i64 OFF_OP  = 36 * MB;    // bf16 [sp=4][B][H][DK][N] flash partials O^T (16 MB)
constexpr i64 OFF_LP  = 68 * MB;    // f32 [sp=4][B][H][N] flash partial row-sums
constexpr i64 OFF_WQP = 69 * MB;    // bf16 512x512 row-perm o'=h*64+dk
constexpr i64 OFF_WKP = 69 * MB + 524288;
constexpr i64 OFF_WVP = 69 * MB + 1048576;
constexpr i64 OFF_WMT = 69 * MB + 1572864;  // bf16 [c'=512][o=512] Wm^T col-permuted
constexpr i64 OFF_W1A = 71 * MB;    // bf16 [1024][512] W1 cols 0:512
constexpr i64 OFF_W1C = 72 * MB;    // bf16 [1024][1024]: cols 0:512 = W1a*Wm, cols 512: = W1b
constexpr i64 OFF_W2B = 74 * MB;    // bf16 512x1024
constexpr i64 OFF_BQP = 75 * MB;    // f32 512 (permuted)
constexpr i64 OFF_BKP = 75 * MB + 2048;
constexpr i64 OFF_BVP = 75 * MB + 4096;
constexpr i64 OFF_BNA = 75 * MB + 8192;   // f32 1024 BN scale
constexpr i64 OFF_BNC = 75 * MB + 12288;  // f32 1024 BN shift (incl b1 AND W1a*bm)
constexpr i64 OFF_MSK = 76 * MB;    // bit-packed mask u32 [B][N][64] (u64 rows per mt)

DEV u16 f2bf(float f) {  // round-to-nearest-even f32->bf16
  u32 u = __float_as_uint(f);
  u = u + 0x7FFFu + ((u >> 16) & 1u);
  return (u16)(u >> 16);
}

DEV float bf2f(u16 u) { return __uint_as_float(((u32)u) << 16); }
DEV float bf2f32(u32 u) { return __uint_as_float(u << 16); }

// pack two f32 -> two bf16 (truncation) in ONE v_perm_b32; lo -> low 16 bits
DEV u32 packbf(float lo, float hi) {
  return __builtin_amdgcn_perm(__float_as_uint(hi), __float_as_uint(lo), 0x07060302u);
}

DEV float fexp2(float x) {
#if __has_builtin(__builtin_amdgcn_exp2f)
  return __builtin_amdgcn_exp2f(x);
#else
  return exp2f(x);
#endif
}

DEV bf16x8 ldfrag(const u16* p) {  // 16B-aligned LDS fragment load
  bf16x8 v;
  __builtin_memcpy(&v, __builtin_assume_aligned(p, 16), 16);
  return v;
}

DEV bf16x8 ldfrag2(const u16* p0, const u16* p1) {  // two 8B LDS loads -> one frag
  bf16x8 v;
  __builtin_memcpy(&v, __builtin_assume_aligned(p0, 8), 8);
  __builtin_memcpy((char*)&v + 8, __builtin_assume_aligned(p1, 8), 8);
  return v;
}

DEV bf16x8 ones8() {  // bf16 1.0 x8
  u16x8 u = {0x3F80, 0x3F80, 0x3F80, 0x3F80, 0x3F80, 0x3F80, 0x3F80, 0x3F80};
  bf16x8 v;
  __builtin_memcpy(&v, &u, 16);
  return v;
}

// async global->LDS, 16B per lane; LDS dest = wave-uniform base + lane*16
DEV void gload16(const void* g, void* lds) {
  __builtin_amdgcn_global_load_lds((__attribute__((address_space(1))) void*)g,
                                   (__attribute__((address_space(3))) void*)lds, 16, 0, 0);
}

DEV f32x4 mfma16(bf16x8 a, bf16x8 b, f32x4 c) {
  return __builtin_amdgcn_mfma_f32_16x16x32_bf16(a, b, c, 0, 0, 0);
}

DEV f32x16 mfma32(bf16x8 a, bf16x8 b, f32x16 c) {
  return __builtin_amdgcn_mfma_f32_32x32x16_bf16(a, b, c, 0, 0, 0);
}

// ---------------- prep_all: weights, BN fold, mask pack, input transpose ----------------
__global__ __launch_bounds__(256) void prep_all(
    const float* __restrict__ Wq, const float* __restrict__ Wk, const float* __restrict__ Wv,
    const float* __restrict__ Wm, const float* __restrict__ W1, const float* __restrict__ W2,
    const float* __restrict__ bq, const float* __restrict__ bk, const float* __restrict__ bv,
    const float* __restrict__ bm, const float* __restrict__ b1, const float* __restrict__ gamma_,
    const float* __restrict__ beta_, const float* __restrict__ rmean,
    const float* __restrict__ rvar, const int* __restrict__ mask,
    const float* __restrict__ iq, const float* __restrict__ kt, const float* __restrict__ vv,
    u16* __restrict__ wqp, u16* __restrict__ wkp, u16* __restrict__ wvp, u16* __restrict__ wmt,
    u16* __restrict__ w1a, u16* __restrict__ w1c, u16* __restrict__ w2b,
    float* __restrict__ bqp, float* __restrict__ bkp, float* __restrict__ bvp,
    float* __restrict__ bna, float* __restrict__ bnc, u32* __restrict__ mw,
    u16* __restrict__ cat, u16* __restrict__ xkt, u16* __restrict__ xvt) {
  __shared__ float tile[32][33];
  const int blk = blockIdx.x, t = threadIdx.x;
  if (blk < 768) {  // Wq/Wk/Wv row-permute: dst row o'=h*64+dk <- src row dk*8+h
    const int which = blk >> 8, lb = blk & 255;
    const float* W = which == 0 ? Wq : (which == 1 ? Wk : Wv);
    u16* dst = which == 0 ? wqp : (which == 1 ? wkp : wvp);
    for (int e = lb * 256 + t; e < 262144; e += 65536) {
      int op = e >> 9, i = e & 511;
      int dk = op & 63, h = op >> 6;
      dst[e] = f2bf(W[(dk * 8 + h) * 512 + i]);
    }
  } else if (blk < 1024) {  // wmt[c'][o] = Wm[o][dk*8+h], c'=h*64+dk
    const int lb = blk - 768;
    for (int e = lb * 256 + t; e < 262144; e += 65536) {
      int cp = e >> 9, o = e & 511;
      int dk = cp & 63, h = cp >> 6;
      wmt[e] = f2bf(Wm[o * 512 + dk * 8 + h]);
    }
  } else if (blk < 1280) {  // w1a = W1[:, 0:512]
    const int lb = blk - 1024;
    for (int e = lb * 256 + t; e < 524288; e += 65536) {
      int row = e >> 9, o = e & 511;
      w1a[e] = f2bf(W1[(i64)row * 1024 + o]);
    }
  } else if (blk < 1536) {  // w1c[:, 512:1024] = W1[:, 512:1024]
    const int lb = blk - 1280;
    for (int e = lb * 256 + t; e < 524288; e += 65536) {
      int row = e >> 9, j = e & 511;
      w1c[(i64)row * 1024 + 512 + j] = f2bf(W1[(i64)row * 1024 + 512 + j]);
    }
  } else if (blk < 1792) {  // W2
    const int lb = blk - 1536;
    for (int e = lb * 256 + t; e < 524288; e += 65536) w2b[e] = f2bf(W2[e]);
  } else if (blk < 1808) {  // BN fold incl. s_e = sum_o W1a[e][o]*bm[o]
    __shared__ float sm[4][64];
    const int base = (blk - 1792) * 64;
    const int el = t & 63, oq = t >> 6;
    const float* wrow = W1 + (i64)(base + el) * 1024 + oq * 128;
    const float* bmq = bm + oq * 128;
    float s = 0.f;
#pragma unroll 8
    for (int j = 0; j < 128; j += 4) {
      float4 x = *(const float4*)(wrow + j);
      float4 y = *(const float4*)(bmq + j);
      s += x.x * y.x + x.y * y.y + x.z * y.z + x.w * y.w;
    }
    sm[oq][el] = s;
    __syncthreads();
    if (t < 64) {
      int e = base + t;
      float a = gamma_[e] * rsqrtf(rvar[e] + 1e-5f);
      bna[e] = a;
      bnc[e] = (b1[e] - rmean[e]) * a + beta_[e] + a * (sm[0][t] + sm[1][t] + sm[2][t] + sm[3][t]);
    }
  } else if (blk == 1808) {  // permuted projection biases
    for (int e = t; e < 512; e += 256) {
      int src = (e & 63) * 8 + (e >> 6);
      bqp[e] = bq[src]; bkp[e] = bk[src]; bvp[e] = bv[src];
    }
  } else if (blk < 2833) {  // mask pack: each lane packs its own 32 consecutive ints -> one u32
    const int tid = (blk - 1809) * 256 + t;  // [0, 262144)
    const i64 base = (i64)tid * 32;
    const int4* mp = (const int4*)(mask + base);
    u32 word = 0;
#pragma unroll
    for (int j = 0; j < 8; ++j) {
      int4 x = mp[j];
      u32 nib = (x.x != 0 ? 1u : 0u) | (x.y != 0 ? 2u : 0u) | (x.z != 0 ? 4u : 0u) |
                (x.w != 0 ? 8u : 0u);
      word |= nib << (j * 4);
    }
    mw[tid] = word;
  } else {  // transpose+convert: (B,D,N) f32 -> (B,N,D) bf16, packed u32 stores
    const int idx = blk - 2833;
    const int bx = idx & 63, by = (idx >> 6) & 15, bz = idx >> 10;
    const int tensor = bz >> 1, b = bz & 1;
    const float* src = (tensor == 0 ? iq : (tensor == 1 ? kt : vv)) + (i64)b * DD * NN;
    u16* dst; i64 ldd; int coff;
    if (tensor == 0)      { dst = cat + (i64)b * NN * D2; ldd = D2; coff = DD; }
    else if (tensor == 1) { dst = xkt + (i64)b * NN * DD; ldd = DD; coff = 0; }
    else                  { dst = xvt + (i64)b * NN * DD; ldd = DD; coff = 0; }
    const int x0 = bx * 32, y0 = by * 32;
    const int col = t & 31, rg = t >> 5;
#pragma unroll
    for (int i = 0; i < 4; ++i) {
      int row = rg + i * 8;
      tile[row][col] = src[(i64)(y0 + row) * NN + x0 + col];
    }
    __syncthreads();
    const int dp = t & 15, rbase = t >> 4;
    u32* dst32 = (u32*)dst;
    const i64 ldw = ldd >> 1;
    const int cw = (coff + y0) >> 1;
#pragma unroll
    for (int i = 0; i < 2; ++i) {
      int rr = rbase + i * 16;
      dst32[(i64)(x0 + rr) * ldw + cw + dp] = packbf(tile[2 * dp][rr], tile[2 * dp + 1][rr]);
    }
  }
}

// ---------------- shared GEMM core: (AM*32)x(AN*32) tile, BK=64, 4 waves 2x2 ----------------
template <int AM, int AN>
DEV void gemm_core(const u16* __restrict__ A, i64 lda, const u16* __restrict__ Bp, i64 ldb,
                   int K, u16* As, u16* Bs, f32x4 (&acc)[AM][AN]) {
  constexpr int BM = AM * 32, BN = AN * 32;
  const int t = threadIdx.x, w = t >> 6, l = t & 63, quad = l >> 4, l15 = l & 15;
  const int wm = (w >> 1) * AM * 16, wn = (w & 1) * AN * 16;
  for (int kk = 0; kk < K; kk += 64) {
    __syncthreads();
#pragma unroll
    for (int j = 0; j < BM / 32; ++j) {
      int ch = j * 256 + w * 64 + l, r = ch >> 3, c = ch & 7;
      gload16(A + (i64)r * lda + kk + ((c ^ (r & 7)) << 3), As + (j * 256 + w * 64) * 8);
    }
#pragma unroll
    for (int j = 0; j < BN / 32; ++j) {
      int ch = j * 256 + w * 64 + l, r = ch >> 3, c = ch & 7;
      gload16(Bp + (i64)r * ldb + kk + ((c ^ (r & 7)) << 3), Bs + (j * 256 + w * 64) * 8);
    }
    __syncthreads();
#pragma unroll
    for (int kc = 0; kc < 2; ++kc) {
      const int sw = ((kc * 4 + quad) ^ (l15 & 7)) << 3;
      bf16x8 af[AM], bfr[AN];
#pragma unroll
      for (int i = 0; i < AM; ++i) af[i] = ldfrag(&As[(wm + i * 16 + l15) * 64 + sw]);
#pragma unroll
      for (int j = 0; j < AN; ++j) bfr[j] = ldfrag(&Bs[(wn + j * 16 + l15) * 64 + sw]);
#pragma unroll
      for (int i = 0; i < AM; ++i)
#pragma unroll
        for (int j = 0; j < AN; ++j) acc[i][j] = mfma16(af[i], bfr[j], acc[i][j]);
    }
  }
}

// ---------------- fused Q/K/V projection + Wc weight-GEMM (z==6) ----------------
__global__ __launch_bounds__(256) void qkv_gemm(const u16* __restrict__ cat,
                                                const u16* __restrict__ xkt,
                                                const u16* __restrict__ xvt,
                                                const u16* __restrict__ wqp,
                                                const u16* __restrict__ wkp,
                                                const u16* __restrict__ wvp,
                                                const u16* __restrict__ w1a,
                                                const u16* __restrict__ wmt,
                                                const float* __restrict__ bqp,
                                                const float* __restrict__ bkp,
                                                const float* __restrict__ bvp,
                                                u16* __restrict__ qh, u16* __restrict__ kh,
                                                u16* __restrict__ vt, u16* __restrict__ w1c) {
  __shared__ __align__(16) u16 As[128 * 64];
  __shared__ __align__(16) u16 Bs[64 * 64];
  const int z = blockIdx.z, b = z & 1;
  const int op = (z == 6) ? 3 : (z >> 1);
  const int t = threadIdx.x, w = t >> 6, l = t & 63, quad = l >> 4, l15 = l & 15;
  const int wm = (w >> 1) * 64, wn = (w & 1) * 32;
  int mx, ny;
  const u16 *A, *Bp;
  i64 lda, ldb;
  if (op < 2) {  // Q/K: A = activations [2048][512], B = W [512][512]
    mx = blockIdx.x; ny = blockIdx.y;
    A = (op == 0 ? cat + DD : xkt);
    lda = (op == 0 ? D2 : DD);
    A += (i64)b * NN * lda + (i64)mx * 128 * lda;
    Bp = (op == 0 ? wqp : wkp) + (i64)ny * 64 * DD;
    ldb = DD;
  } else if (op == 2) {  // V: A = Wv [512][512], B = value^T [2048][512]
    int f = blockIdx.x * 8 + blockIdx.y;
    mx = f >> 5; ny = f & 31;
    A = wvp + (i64)mx * 128 * DD; lda = DD;
    Bp = xvt + (i64)b * NN * DD + (i64)ny * 64 * DD; ldb = DD;
  } else {  // Wc = W1a * wmt^T : [1024 x 512], K=512
    if (blockIdx.x >= 8) return;
    mx = blockIdx.x; ny = blockIdx.y;
    A = w1a + (i64)mx * 128 * DD; lda = DD;
    Bp = wmt + (i64)ny * 64 * DD; ldb = DD;
  }
  f32x4 acc[4][2] = {};
  gemm_core<4, 2>(A, lda, Bp, ldb, DD, As, Bs, acc);

  const int rowBase = mx * 128 + wm + quad * 4;
  const int colBase = ny * 64 + wn + l15;
  if (op < 2) {  // head scatter: col=h*64+dk -> [b][h][n][dk]; Q scaled by QSC
    const float* bias = (op == 0 ? bqp : bkp);
    const float sc = (op == 0 ? QSC : 1.f);
    u16* dst = (op == 0 ? qh : kh) + (i64)b * HH * NN * DKc;
#pragma unroll
    for (int j = 0; j < 2; ++j) {
      const int col = colBase + j * 16;
      const float cA = bias[col];
#pragma unroll
      for (int i = 0; i < 4; ++i)
#pragma unroll
        for (int r = 0; r < 4; ++r) {
          const int row = rowBase + i * 16 + r;
          dst[(i64)(col >> 6) * (NN * 64) + (i64)row * 64 + (col & 63)] =
              f2bf((acc[i][j][r] + cA) * sc);
        }
    }
  } else if (op == 2) {  // V: row bias, store [b][o'][m] (natural m)
    u16* dst = vt + (i64)b * HH * DKc * NN;
#pragma unroll
    for (int j = 0; j < 2; ++j) {
      const int col = colBase + j * 16;
#pragma unroll
      for (int i = 0; i < 4; ++i)
#pragma unroll
        for (int r = 0; r < 4; ++r) {
          const int row = rowBase + i * 16 + r;
          dst[(i64)row * NN + col] = f2bf(acc[i][j][r] + bvp[row]);
        }
    }
  } else {  // Wc plain store -> w1c[:, 0:512]
#pragma unroll
    for (int j = 0; j < 2; ++j) {
      const int col = colBase + j * 16;
#pragma unroll
      for (int i = 0; i < 4; ++i)
#pragma unroll
        for (int r = 0; r < 4; ++r) {
          const int row = rowBase + i * 16 + r;
          w1c[(i64)row * D2 + col] = f2bf(acc[i][j][r]);
        }
    }
  }
}

// ---------------- generic gemm_bt: C[m][n] = A[m][:]·B[n][:] (+epilogue) ----------------
struct GArgs {
  const u16* A; i64 lda, sAb;
  const u16* B; i64 ldb, sBb;
  void* C; i64 ldc, sCb;
  const float* p1; const float* p2;
  int K;
};

template <int MODE, int AM, int AN, int SWZ>
__global__ __launch_bounds__(256) void gemm_bt(GArgs g) {
  __shared__ __align__(16) u16 As[AM * 32 * 64];
  __shared__ __align__(16) u16 Bs[AN * 32 * 64];
  const int t = threadIdx.x, w = t >> 6, l = t & 63, quad = l >> 4, l15 = l & 15;
  const int wm = (w >> 1) * AM * 16, wn = (w & 1) * AN * 16;
  int bx = blockIdx.x, by = blockIdx.y, bz = blockIdx.z;
  if (SWZ == 1) {  // flat = bx + 8by + 256bz; pin same-by blocks to one XCD slot
    const int i = bx + (by << 3) + (bz << 8);
    const int slot = i & 7, jj = i >> 3;
    by = slot + ((jj & 3) << 3);
    const int j2 = jj >> 2;
    bx = j2 & 7;
    bz = j2 >> 3;
  }
  const u16* A = g.A + (i64)bz * g.sAb + (i64)bx * (AM * 32) * g.lda;
  const u16* Bp = g.B + (i64)bz * g.sBb + (i64)by * (AN * 32) * g.ldb;
  f32x4 acc[AM][AN] = {};
  gemm_core<AM, AN>(A, g.lda, Bp, g.ldb, g.K, As, Bs, acc);

  const int rowBase = bx * (AM * 32) + wm + quad * 4;
  const int colBase = by * (AN * 32) + wn + l15;
#pragma unroll
  for (int j = 0; j < AN; ++j) {
    const int col = colBase + j * 16;
    float cA = 0.f, cB = 0.f;
    if (MODE == 3) { cA = g.p1[col]; cB = g.p2[col]; }
#pragma unroll
    for (int i = 0; i < AM; ++i) {
#pragma unroll
      for (int r = 0; r < 4; ++r) {
        const int row = rowBase + i * 16 + r;
        float v = acc[i][j][r];
        if (MODE == 3) {  // BN+ReLU, bf16 out
          float x = v * cA + cB;
          ((u16*)g.C + (i64)bz * g.sCb)[(i64)row * g.ldc + col] = f2bf(x > 0.f ? x : 0.f);
        } else {  // MODE 4: fp32 out, row bias (W2 -> d_out)
          ((float*)g.C + (i64)bz * g.sCb)[(i64)row * g.ldc + col] = v + g.p1[row];
        }
      }
    }
  }
}

// ---------------- flash attention v7: transposed-S, register-resident P, no P round-trip ----------------
// S^T = mfma(A=K, B=Q); P^T stays in C-regs == valid B-operand for O^T = mfma(A=V^T, P^T).
__global__ __launch_bounds__(256) void flash_attn(const u16* __restrict__ Qh,
                                                  const u16* __restrict__ Kh,
                                                  const u16* __restrict__ Vt,
                                                  const u64* __restrict__ MW64,
                                                  u16* __restrict__ Opart,
                                                  float* __restrict__ Lp) {
  __shared__ __align__(16) u16 Ks[64 * 64];
  __shared__ __align__(16) u16 Vs[64 * 64];
  const int t = threadIdx.x, w = t >> 6, l = t & 63, l31 = l & 31, lh = l >> 5;
  // flat decode pinning all blocks of head h to one XCD slot (RR dispatch)
  const int flat = blockIdx.x;
  const int h = flat & 7;
  const int j = flat >> 3;
  const int nt = j & 15, zz = j >> 4;
  const int b = zz >> 2, sp = zz & 3;
  const int n = nt * 128 + w * 32 + l31;  // this lane's q-row
  const u16* Qb = Qh + ((i64)(b * HH + h) * NN + nt * 128 + w * 32) * 64;
  const u16* Kb = Kh + (i64)(b * HH + h) * NN * 64;
  const u16* Vb = Vt + (i64)(b * HH + h) * 64 * NN;
  const u64* mwp = MW64 + (i64)(b * NN + n) * 32;
  const bf16x8 ONE = ones8();
  // Q fragments (B-operand): lane q=l31, k = kc*16 + lh*8 + j
  bf16x8 qf[4];
#pragma unroll
  for (int kc = 0; kc < 4; ++kc)
    __builtin_memcpy(&qf[kc], Qb + (i64)l31 * 64 + kc * 16 + lh * 8, 16);

  f32x16 oacc0 = {}, oacc1 = {}, lacc = {};
  for (int mt = sp * 8; mt < sp * 8 + 8; ++mt) {
    __syncthreads();
#pragma unroll
    for (int j2 = 0; j2 < 2; ++j2) {  // stage K,V (64x64 each, chunk-swizzled)
      int ch = j2 * 256 + t, r = ch >> 3, c = ch & 7;
      gload16(Kb + (i64)(mt * 64 + r) * 64 + ((c ^ (r & 7)) << 3), &Ks[ch * 8]);
      gload16(Vb + (i64)r * NN + mt * 64 + ((c ^ (r & 7)) << 3), &Vs[ch * 8]);
    }
    __syncthreads();
    // S^T = K Q^T : C lane = q, regs = kv rows. Two kv tiles (0-31, 32-63).
    f32x16 s0 = {}, s1 = {};
#pragma unroll
    for (int kc = 0; kc < 4; ++kc) {
      const int sw = l31 & 7;
      bf16x8 k0 = ldfrag(&Ks[l31 * 64 + (((kc * 2 + lh) ^ sw) << 3)]);
      bf16x8 k1 = ldfrag(&Ks[(32 + l31) * 64 + (((kc * 2 + lh) ^ sw) << 3)]);
      s0 = mfma32(k0, qf[kc], s0);
      s1 = mfma32(k1, qf[kc], s1);
    }
    // p = exp2(s) masked; pack C-reg pairs in order -> B-operand frags pf[0..3]
    const u64 mrow = mwp[mt];
    u32 pw[16];
#pragma unroll
    for (int k = 0; k < 8; ++k) {
      const int kvb = ((2 * k) & 3) + 8 * ((2 * k) >> 2) + 4 * lh;
      u64 sh = mrow >> kvb;
      u32 mA = (((u32)sh & 1u) | (((u32)sh & 2u) << 15)) * 0xFFFFu;
      u32 shh = (u32)(sh >> 32);
      u32 mB = ((shh & 1u) | ((shh & 2u) << 15)) * 0xFFFFu;
      pw[k] = packbf(fexp2(s0[2 * k]), fexp2(s0[2 * k + 1])) & mA;
      pw[8 + k] = packbf(fexp2(s1[2 * k]), fexp2(s1[2 * k + 1])) & mB;
    }
    bf16x8 pf[4];
#pragma unroll
    for (int c = 0; c < 4; ++c) __builtin_memcpy(&pf[c], &pw[c * 4], 16);
#pragma unroll
    for (int c = 0; c < 4; ++c) lacc = mfma32(ONE, pf[c], lacc);  // l[q] per lane
    // O^T += V^T P^T : A = V^T frags with the sigma k-slot layout matching pf
#pragma unroll
    for (int c = 0; c < 4; ++c) {
      const int sw0 = l31 & 7;
      const u16* r0 = &Vs[l31 * 64];
      const u16* r1 = &Vs[(32 + l31) * 64];
      bf16x8 v0 = ldfrag2(r0 + (((2 * c) ^ sw0) << 3) + lh * 4,
                          r0 + (((2 * c + 1) ^ sw0) << 3) + lh * 4);
      bf16x8 v1 = ldfrag2(r1 + (((2 * c) ^ sw0) << 3) + lh * 4,
                          r1 + (((2 * c + 1) ^ sw0) << 3) + lh * 4);
      oacc0 = mfma32(v0, pf[c], oacc0);
      oacc1 = mfma32(v1, pf[c], oacc1);
    }
  }
  // epilogue: O^T partials -> Opart[sp][b][h][d][n] (lane=n, coalesced); Lp row sums
  u16* OpT = Opart + ((i64)((sp * BB + b) * HH + h) * 64) * NN;
#pragma unroll
  for (int r = 0; r < 16; ++r) {
    const int d0 = (r & 3) + 8 * (r >> 2) + 4 * lh;
    OpT[(i64)d0 * NN + n] = f2bf(oacc0[r]);
    OpT[(i64)(d0 + 32) * NN + n] = f2bf(oacc1[r]);
  }
  if (lh == 0) Lp[((i64)(sp * BB + b) * HH + h) * NN + n] = lacc[0];
}

// ---------------- combine: cat[n][h*64+d] = sum_sp O^T[d][n] / sum_sp l[n], LDS transpose ----------------
__global__ __launch_bounds__(256) void combine(const u16* __restrict__ Opart,
                                               const float* __restrict__ Lp,
                                               u16* __restrict__ cat) {
  __shared__ float lt[128 * 65];
  const int t = threadIdx.x;
  const int nt = blockIdx.x, bh = blockIdx.y;
  const int b = bh >> 3, h = bh & 7;
  const int n0 = nt * 128;
  const i64 sstride = (i64)BB * HH * 64 * NN;
  const u16* Ob = Opart + ((i64)(b * HH + h) * 64) * NN;
  // phase A: sum 4 sp partials, u32-pair loads, store [n][d] into LDS
#pragma unroll
  for (int i = 0; i < 16; ++i) {
    const int idx = i * 256 + t;  // [0, 4096): d x 64 n-pairs
    const int d = idx >> 6, np = idx & 63;
    float sa = 0.f, sb = 0.f;
#pragma unroll
    for (int s = 0; s < 4; ++s) {
      u32 v;
      __builtin_memcpy(&v, Ob + s * sstride + (i64)d * NN + n0 + 2 * np, 4);
      sa += bf2f32(v & 0xFFFFu);
      sb += bf2f32(v >> 16);
    }
    lt[(2 * np) * 65 + d] = sa;
    lt[(2 * np + 1) * 65 + d] = sb;
  }
  __syncthreads();
  // phase B: normalize rows and write cat (u32-packed, coalesced along d)
  u32* catw = (u32*)cat;
#pragma unroll
  for (int i = 0; i < 16; ++i) {
    const int idx = i * 256 + t;  // [0, 4096): n x 32 d-pairs
    const int nn = idx >> 5, dp = idx & 31;
    float lsum = 0.f;
#pragma unroll
    for (int s = 0; s < 4; ++s) lsum += Lp[((i64)(s * BB + b) * HH + h) * NN + n0 + nn];
    const float rl = __builtin_amdgcn_rcpf(lsum);
    u32 pv = packbf(lt[nn * 65 + 2 * dp] * rl, lt[nn * 65 + 2 * dp + 1] * rl);
    catw[((i64)b * NN + n0 + nn) * (D2 / 2) + h * 32 + dp] = pv;
  }
}

extern "C" void kernel_launch(void* const* d_in, const int* in_sizes, int n_in,
                              void* d_out, int out_size, void* d_ws, size_t ws_size,
                              hipStream_t stream) {
  (void)in_sizes; (void)n_in; (void)out_size; (void)ws_size;
  const float* iq    = (const float*)d_in[0];
  const float* kt    = (const float*)d_in[1];
  const float* vv    = (const float*)d_in[2];
  const int*   mask  = (const int*)d_in[3];
  const float* Wq    = (const float*)d_in[4];
  const float* bq    = (const float*)d_in[5];
  const float* Wk    = (const float*)d_in[6];
  const float* bk    = (const float*)d_in[7];
  const float* Wv    = (const float*)d_in[8];
  const float* bv    = (const float*)d_in[9];
  const float* Wm    = (const float*)d_in[10];
  const float* bm    = (const float*)d_in[11];
  const float* W1    = (const float*)d_in[12];
  const float* b1    = (const float*)d_in[13];
  const float* gamma_= (const float*)d_in[14];
  const float* beta_ = (const float*)d_in[15];
  const float* rmean = (const float*)d_in[16];
  const float* rvar  = (const float*)d_in[17];
  const float* W2    = (const float*)d_in[18];
  const float* b2    = (const float*)d_in[19];

  char* ws = (char*)d_ws;
  u16* cat = (u16*)(ws + OFF_CAT);
  u16* xkt = (u16*)(ws + OFF_XKT);
  u16* xvt = (u16*)(ws + OFF_XVT);
  u16* qh  = (u16*)(ws + OFF_QH);
  u16* kh  = (u16*)(ws + OFF_KH);
  u16* vt  = (u16*)(ws + OFF_VT);
  u16* ht  = (u16*)(ws + OFF_HT);
  u16* opart = (u16*)(ws + OFF_OP);
  float* lp  = (float*)(ws + OFF_LP);
  u16* wqp = (u16*)(ws + OFF_WQP);
  u16* wkp = (u16*)(ws + OFF_WKP);
  u16* wvp = (u16*)(ws + OFF_WVP);
  u16* wmt = (u16*)(ws + OFF_WMT);
  u16* w1a = (u16*)(ws + OFF_W1A);
  u16* w1c = (u16*)(ws + OFF_W1C);
  u16* w2b = (u16*)(ws + OFF_W2B);
  float* bqp = (float*)(ws + OFF_BQP);
  float* bkp = (float*)(ws + OFF_BKP);
  float* bvp = (float*)(ws + OFF_BVP);
  float* bna = (float*)(ws + OFF_BNA);
  float* bnc = (float*)(ws + OFF_BNC);
  u32* mw = (u32*)(ws + OFF_MSK);

  // 1. prep (weights/BN/mask) + input transpose, one launch
  prep_all<<<8977, 256, 0, stream>>>(Wq, Wk, Wv, Wm, W1, W2, bq, bk, bv, bm, b1, gamma_, beta_,
                                     rmean, rvar, mask, iq, kt, vv, wqp, wkp, wvp, wmt, w1a, w1c,
                                     w2b, bqp, bkp, bvp, bna, bnc, mw, cat, xkt, xvt);
  // 2. fused Q/K/V projections + Wc weight-GEMM (z==6)
  qkv_gemm<<<dim3(16, 8, 7), 256, 0, stream>>>(cat, xkt, xvt, wqp, wkp, wvp, w1a, wmt,
                                               bqp, bkp, bvp, qh, kh, vt, w1c);
  // 3. flash v7: register-P, KV-split-4, head-pinned XCD dispatch
  flash_attn<<<1024, 256, 0, stream>>>(qh, kh, vt, (const u64*)mw, opart, lp);
  // 4. combine (transposing) into cat[:, 0:512]
  combine<<<dim3(16, 16), 256, 0, stream>>>(opart, lp, cat);
  // 5. W1' + BN + ReLU, batch-merged M=4096, 128x64 tiles
  GArgs wa{cat, D2, 0, w1c, D2, 0, ht, D2, 0, bna, bnc, D2};
  gemm_bt<3, 4, 2, 0><<<dim3(32, 16, 1), 256, 0, stream>>>(wa);
  // 6. W2 -> d_out (fp32), B-tiles XCD-pinned via SWZ
  GArgs w2a{w2b, D2, 0, ht, D2, (i64)NN * D2, d_out, NN, (i64)DD * NN, b2, nullptr, D2};
  gemm_bt<4, 2, 2, 1><<<dim3(8, 32, 2), 256, 0, stream>>>(w2a);
}

// Round 8
// 218.732 us; speedup vs baseline: 1.0163x; 1.0101x over previous
//
#include <hip/hip_runtime.h>

typedef unsigned short u16;
typedef unsigned int u32;
typedef unsigned long long u64;
typedef long long i64;
typedef __bf16 bf16x8 __attribute__((ext_vector_type(8)));
typedef u16 u16x8 __attribute__((ext_vector_type(8)));
typedef float f32x4 __attribute__((ext_vector_type(4)));
typedef float f32x16 __attribute__((ext_vector_type(16)));

#define DEV __device__ __forceinline__

// problem constants (fixed by harness)
constexpr int BB = 2, DD = 512, NN = 2048, HH = 8, DKc = 64, D2 = 1024;

// Q pre-scale: 1/sqrt(64) * log2(e)  (folded into Q so softmax uses native exp2)
constexpr float QSC = 0.125f * 1.44269504088896340736f;

// workspace byte offsets (16B aligned); NO aliasing
constexpr i64 MB = 1048576;
constexpr i64 OFF_CAT = 0;          // bf16 [B][N][D2]; [0:512)=attn (combine), [512:1024)=iq^T
constexpr i64 OFF_XKT = 8 * MB;     // bf16 [B][N][D] key_t^T
constexpr i64 OFF_XVT = 12 * MB;    // bf16 [B][N][D] value^T
constexpr i64 OFF_QH  = 16 * MB;    // bf16 [B][H][N][DK] (Q pre-scaled by QSC)
constexpr i64 OFF_KH  = 20 * MB;    // bf16 [B][H][N][DK]
constexpr i64 OFF_VT  = 24 * MB;    // bf16 [B][H][DK][N]  (natural m)
constexpr i64 OFF_HT  = 28 * MB;    // bf16 [B][N][D2]
constexpr i64 OFF_OP  = 36 * MB;    // bf16 [sp=4][B][H][DK][N] flash partials O^T (16 MB)
constexpr i64 OFF_LP  = 68 * MB;    // f32 [sp=4][B][H][N] flash partial row-sums
constexpr i64 OFF_WQP = 69 * MB;    // bf16 512x512 row-perm o'=h*64+dk
constexpr i64 OFF_WKP = 69 * MB + 524288;
constexpr i64 OFF_WVP = 69 * MB + 1048576;
constexpr i64 OFF_WMT = 69 * MB + 1572864;  // bf16 [c'=512][o=512] Wm^T col-permuted
constexpr i64 OFF_W1A = 71 * MB;    // bf16 [1024][512] W1 cols 0:512
constexpr i64 OFF_W1C = 72 * MB;    // bf16 [1024][1024]: cols 0:512 = W1a*Wm, cols 512: = W1b
constexpr i64 OFF_W2B = 74 * MB;    // bf16 512x1024
constexpr i64 OFF_BQP = 75 * MB;    // f32 512 (permuted)
constexpr i64 OFF_BKP = 75 * MB + 2048;
constexpr i64 OFF_BVP = 75 * MB + 4096;
constexpr i64 OFF_BNA = 75 * MB + 8192;   // f32 1024 BN scale
constexpr i64 OFF_BNC = 75 * MB + 12288;  // f32 1024 BN shift (incl b1 AND W1a*bm)
constexpr i64 OFF_MSK = 76 * MB;    // bit-packed mask u32 [B][N][64] (u64 rows per mt)

DEV u16 f2bf(float f) {  // round-to-nearest-even f32->bf16
  u32 u = __float_as_uint(f);
  u = u + 0x7FFFu + ((u >> 16) & 1u);
  return (u16)(u >> 16);
}

DEV float bf2f(u16 u) { return __uint_as_float(((u32)u) << 16); }
DEV float bf2f32(u32 u) { return __uint_as_float(u << 16); }

// pack two f32 -> two bf16 (truncation) in ONE v_perm_b32; lo -> low 16 bits
DEV u32 packbf(float lo, float hi) {
  return __builtin_amdgcn_perm(__float_as_uint(hi), __float_as_uint(lo), 0x07060302u);
}

DEV float fexp2(float x) {
#if __has_builtin(__builtin_amdgcn_exp2f)
  return __builtin_amdgcn_exp2f(x);
#else
  return exp2f(x);
#endif
}

DEV bf16x8 ldfrag(const u16* p) {  // 16B-aligned LDS fragment load
  bf16x8 v;
  __builtin_memcpy(&v, __builtin_assume_aligned(p, 16), 16);
  return v;
}

DEV bf16x8 ldfrag2(const u16* p0, const u16* p1) {  // two 8B LDS loads -> one frag
  bf16x8 v;
  __builtin_memcpy(&v, __builtin_assume_aligned(p0, 8), 8);
  __builtin_memcpy((char*)&v + 8, __builtin_assume_aligned(p1, 8), 8);
  return v;
}

DEV bf16x8 ones8() {  // bf16 1.0 x8
  u16x8 u = {0x3F80, 0x3F80, 0x3F80, 0x3F80, 0x3F80, 0x3F80, 0x3F80, 0x3F80};
  bf16x8 v;
  __builtin_memcpy(&v, &u, 16);
  return v;
}

// async global->LDS, 16B per lane; LDS dest = wave-uniform base + lane*16
DEV void gload16(const void* g, void* lds) {
  __builtin_amdgcn_global_load_lds((__attribute__((address_space(1))) void*)g,
                                   (__attribute__((address_space(3))) void*)lds, 16, 0, 0);
}

DEV f32x4 mfma16(bf16x8 a, bf16x8 b, f32x4 c) {
  return __builtin_amdgcn_mfma_f32_16x16x32_bf16(a, b, c, 0, 0, 0);
}

DEV f32x16 mfma32(bf16x8 a, bf16x8 b, f32x16 c) {
  return __builtin_amdgcn_mfma_f32_32x32x16_bf16(a, b, c, 0, 0, 0);
}

// ---------------- prep_all: weights, BN fold, mask pack, input transpose ----------------
__global__ __launch_bounds__(256) void prep_all(
    const float* __restrict__ Wq, const float* __restrict__ Wk, const float* __restrict__ Wv,
    const float* __restrict__ Wm, const float* __restrict__ W1, const float* __restrict__ W2,
    const float* __restrict__ bq, const float* __restrict__ bk, const float* __restrict__ bv,
    const float* __restrict__ bm, const float* __restrict__ b1, const float* __restrict__ gamma_,
    const float* __restrict__ beta_, const float* __restrict__ rmean,
    const float* __restrict__ rvar, const int* __restrict__ mask,
    const float* __restrict__ iq, const float* __restrict__ kt, const float* __restrict__ vv,
    u16* __restrict__ wqp, u16* __restrict__ wkp, u16* __restrict__ wvp, u16* __restrict__ wmt,
    u16* __restrict__ w1a, u16* __restrict__ w1c, u16* __restrict__ w2b,
    float* __restrict__ bqp, float* __restrict__ bkp, float* __restrict__ bvp,
    float* __restrict__ bna, float* __restrict__ bnc, u32* __restrict__ mw,
    u16* __restrict__ cat, u16* __restrict__ xkt, u16* __restrict__ xvt) {
  __shared__ float tile[32][33];
  const int blk = blockIdx.x, t = threadIdx.x;
  if (blk < 768) {  // Wq/Wk/Wv row-permute: dst row o'=h*64+dk <- src row dk*8+h
    const int which = blk >> 8, lb = blk & 255;
    const float* W = which == 0 ? Wq : (which == 1 ? Wk : Wv);
    u16* dst = which == 0 ? wqp : (which == 1 ? wkp : wvp);
    for (int e = lb * 256 + t; e < 262144; e += 65536) {
      int op = e >> 9, i = e & 511;
      int dk = op & 63, h = op >> 6;
      dst[e] = f2bf(W[(dk * 8 + h) * 512 + i]);
    }
  } else if (blk < 1024) {  // wmt[c'][o] = Wm[o][dk*8+h], c'=h*64+dk
    const int lb = blk - 768;
    for (int e = lb * 256 + t; e < 262144; e += 65536) {
      int cp = e >> 9, o = e & 511;
      int dk = cp & 63, h = cp >> 6;
      wmt[e] = f2bf(Wm[o * 512 + dk * 8 + h]);
    }
  } else if (blk < 1280) {  // w1a = W1[:, 0:512]
    const int lb = blk - 1024;
    for (int e = lb * 256 + t; e < 524288; e += 65536) {
      int row = e >> 9, o = e & 511;
      w1a[e] = f2bf(W1[(i64)row * 1024 + o]);
    }
  } else if (blk < 1536) {  // w1c[:, 512:1024] = W1[:, 512:1024]
    const int lb = blk - 1280;
    for (int e = lb * 256 + t; e < 524288; e += 65536) {
      int row = e >> 9, j = e & 511;
      w1c[(i64)row * 1024 + 512 + j] = f2bf(W1[(i64)row * 1024 + 512 + j]);
    }
  } else if (blk < 1792) {  // W2
    const int lb = blk - 1536;
    for (int e = lb * 256 + t; e < 524288; e += 65536) w2b[e] = f2bf(W2[e]);
  } else if (blk < 1808) {  // BN fold incl. s_e = sum_o W1a[e][o]*bm[o]
    __shared__ float sm[4][64];
    const int base = (blk - 1792) * 64;
    const int el = t & 63, oq = t >> 6;
    const float* wrow = W1 + (i64)(base + el) * 1024 + oq * 128;
    const float* bmq = bm + oq * 128;
    float s = 0.f;
#pragma unroll 8
    for (int j = 0; j < 128; j += 4) {
      float4 x = *(const float4*)(wrow + j);
      float4 y = *(const float4*)(bmq + j);
      s += x.x * y.x + x.y * y.y + x.z * y.z + x.w * y.w;
    }
    sm[oq][el] = s;
    __syncthreads();
    if (t < 64) {
      int e = base + t;
      float a = gamma_[e] * rsqrtf(rvar[e] + 1e-5f);
      bna[e] = a;
      bnc[e] = (b1[e] - rmean[e]) * a + beta_[e] + a * (sm[0][t] + sm[1][t] + sm[2][t] + sm[3][t]);
    }
  } else if (blk == 1808) {  // permuted projection biases
    for (int e = t; e < 512; e += 256) {
      int src = (e & 63) * 8 + (e >> 6);
      bqp[e] = bq[src]; bkp[e] = bk[src]; bvp[e] = bv[src];
    }
  } else if (blk < 2833) {  // mask pack: each lane packs its own 32 consecutive ints -> one u32
    const int tid = (blk - 1809) * 256 + t;  // [0, 262144)
    const i64 base = (i64)tid * 32;
    const int4* mp = (const int4*)(mask + base);
    u32 word = 0;
#pragma unroll
    for (int j = 0; j < 8; ++j) {
      int4 x = mp[j];
      u32 nib = (x.x != 0 ? 1u : 0u) | (x.y != 0 ? 2u : 0u) | (x.z != 0 ? 4u : 0u) |
                (x.w != 0 ? 8u : 0u);
      word |= nib << (j * 4);
    }
    mw[tid] = word;
  } else {  // transpose+convert: (B,D,N) f32 -> (B,N,D) bf16, packed u32 stores
    const int idx = blk - 2833;
    const int bx = idx & 63, by = (idx >> 6) & 15, bz = idx >> 10;
    const int tensor = bz >> 1, b = bz & 1;
    const float* src = (tensor == 0 ? iq : (tensor == 1 ? kt : vv)) + (i64)b * DD * NN;
    u16* dst; i64 ldd; int coff;
    if (tensor == 0)      { dst = cat + (i64)b * NN * D2; ldd = D2; coff = DD; }
    else if (tensor == 1) { dst = xkt + (i64)b * NN * DD; ldd = DD; coff = 0; }
    else                  { dst = xvt + (i64)b * NN * DD; ldd = DD; coff = 0; }
    const int x0 = bx * 32, y0 = by * 32;
    const int col = t & 31, rg = t >> 5;
#pragma unroll
    for (int i = 0; i < 4; ++i) {
      int row = rg + i * 8;
      tile[row][col] = src[(i64)(y0 + row) * NN + x0 + col];
    }
    __syncthreads();
    const int dp = t & 15, rbase = t >> 4;
    u32* dst32 = (u32*)dst;
    const i64 ldw = ldd >> 1;
    const int cw = (coff + y0) >> 1;
#pragma unroll
    for (int i = 0; i < 2; ++i) {
      int rr = rbase + i * 16;
      dst32[(i64)(x0 + rr) * ldw + cw + dp] = packbf(tile[2 * dp][rr], tile[2 * dp + 1][rr]);
    }
  }
}

// ---------------- shared GEMM core: (AM*32)x(AN*32) tile, BK=64, 4 waves 2x2 ----------------
template <int AM, int AN>
DEV void gemm_core(const u16* __restrict__ A, i64 lda, const u16* __restrict__ Bp, i64 ldb,
                   int K, u16* As, u16* Bs, f32x4 (&acc)[AM][AN]) {
  constexpr int BM = AM * 32, BN = AN * 32;
  const int t = threadIdx.x, w = t >> 6, l = t & 63, quad = l >> 4, l15 = l & 15;
  const int wm = (w >> 1) * AM * 16, wn = (w & 1) * AN * 16;
  for (int kk = 0; kk < K; kk += 64) {
    __syncthreads();
#pragma unroll
    for (int j = 0; j < BM / 32; ++j) {
      int ch = j * 256 + w * 64 + l, r = ch >> 3, c = ch & 7;
      gload16(A + (i64)r * lda + kk + ((c ^ (r & 7)) << 3), As + (j * 256 + w * 64) * 8);
    }
#pragma unroll
    for (int j = 0; j < BN / 32; ++j) {
      int ch = j * 256 + w * 64 + l, r = ch >> 3, c = ch & 7;
      gload16(Bp + (i64)r * ldb + kk + ((c ^ (r & 7)) << 3), Bs + (j * 256 + w * 64) * 8);
    }
    __syncthreads();
#pragma unroll
    for (int kc = 0; kc < 2; ++kc) {
      const int sw = ((kc * 4 + quad) ^ (l15 & 7)) << 3;
      bf16x8 af[AM], bfr[AN];
#pragma unroll
      for (int i = 0; i < AM; ++i) af[i] = ldfrag(&As[(wm + i * 16 + l15) * 64 + sw]);
#pragma unroll
      for (int j = 0; j < AN; ++j) bfr[j] = ldfrag(&Bs[(wn + j * 16 + l15) * 64 + sw]);
#pragma unroll
      for (int i = 0; i < AM; ++i)
#pragma unroll
        for (int j = 0; j < AN; ++j) acc[i][j] = mfma16(af[i], bfr[j], acc[i][j]);
    }
  }
}

// ---------------- fused Q/K/V projection + Wc weight-GEMM, 128x128 tiles, flat grid 416 ----------------
__global__ __launch_bounds__(256) void qkv_gemm(const u16* __restrict__ cat,
                                                const u16* __restrict__ xkt,
                                                const u16* __restrict__ xvt,
                                                const u16* __restrict__ wqp,
                                                const u16* __restrict__ wkp,
                                                const u16* __restrict__ wvp,
                                                const u16* __restrict__ w1a,
                                                const u16* __restrict__ wmt,
                                                const float* __restrict__ bqp,
                                                const float* __restrict__ bkp,
                                                const float* __restrict__ bvp,
                                                u16* __restrict__ qh, u16* __restrict__ kh,
                                                u16* __restrict__ vt, u16* __restrict__ w1c) {
  __shared__ __align__(16) u16 As[128 * 64];
  __shared__ __align__(16) u16 Bs[128 * 64];
  const int flat = blockIdx.x;
  const int t = threadIdx.x, w = t >> 6, l = t & 63, quad = l >> 4, l15 = l & 15;
  const int wm = (w >> 1) * 64, wn = (w & 1) * 64;
  int op, b = 0, mx, ny;
  if (flat < 256) {        // Q (0..127) / K (128..255): M=2048, N=512 -> 16x4 per b
    op = flat >> 7;
    b = (flat >> 6) & 1;
    const int r = flat & 63;
    mx = r >> 2; ny = r & 3;
  } else if (flat < 384) {  // V: M=512, N=2048 -> 4x16 per b
    op = 2;
    const int r = flat - 256;
    b = r >> 6;
    const int rr = r & 63;
    mx = rr >> 4; ny = rr & 15;
  } else {                  // Wc: M=1024, N=512 -> 8x4
    op = 3;
    const int r = flat - 384;
    mx = r >> 2; ny = r & 3;
  }
  const u16 *A, *Bp;
  i64 lda, ldb;
  if (op < 2) {
    A = (op == 0 ? cat + DD : xkt);
    lda = (op == 0 ? D2 : DD);
    A += (i64)b * NN * lda + (i64)mx * 128 * lda;
    Bp = (op == 0 ? wqp : wkp) + (i64)ny * 128 * DD;
    ldb = DD;
  } else if (op == 2) {
    A = wvp + (i64)mx * 128 * DD; lda = DD;
    Bp = xvt + (i64)b * NN * DD + (i64)ny * 128 * DD; ldb = DD;
  } else {
    A = w1a + (i64)mx * 128 * DD; lda = DD;
    Bp = wmt + (i64)ny * 128 * DD; ldb = DD;
  }
  f32x4 acc[4][4] = {};
  gemm_core<4, 4>(A, lda, Bp, ldb, DD, As, Bs, acc);

  const int rowBase = mx * 128 + wm + quad * 4;
  const int colBase = ny * 128 + wn + l15;
  if (op < 2) {  // head scatter: col=h*64+dk -> [b][h][n][dk]; Q scaled by QSC
    const float* bias = (op == 0 ? bqp : bkp);
    const float sc = (op == 0 ? QSC : 1.f);
    u16* dst = (op == 0 ? qh : kh) + (i64)b * HH * NN * DKc;
#pragma unroll
    for (int j = 0; j < 4; ++j) {
      const int col = colBase + j * 16;
      const float cA = bias[col];
#pragma unroll
      for (int i = 0; i < 4; ++i)
#pragma unroll
        for (int r = 0; r < 4; ++r) {
          const int row = rowBase + i * 16 + r;
          dst[(i64)(col >> 6) * (NN * 64) + (i64)row * 64 + (col & 63)] =
              f2bf((acc[i][j][r] + cA) * sc);
        }
    }
  } else if (op == 2) {  // V: row bias, store [b][o'][m] (natural m)
    u16* dst = vt + (i64)b * HH * DKc * NN;
#pragma unroll
    for (int j = 0; j < 4; ++j) {
      const int col = colBase + j * 16;
#pragma unroll
      for (int i = 0; i < 4; ++i)
#pragma unroll
        for (int r = 0; r < 4; ++r) {
          const int row = rowBase + i * 16 + r;
          dst[(i64)row * NN + col] = f2bf(acc[i][j][r] + bvp[row]);
        }
    }
  } else {  // Wc plain store -> w1c[:, 0:512]
#pragma unroll
    for (int j = 0; j < 4; ++j) {
      const int col = colBase + j * 16;
#pragma unroll
      for (int i = 0; i < 4; ++i)
#pragma unroll
        for (int r = 0; r < 4; ++r) {
          const int row = rowBase + i * 16 + r;
          w1c[(i64)row * D2 + col] = f2bf(acc[i][j][r]);
        }
    }
  }
}

// ---------------- generic gemm_bt: C[m][n] = A[m][:]·B[n][:] (+epilogue) ----------------
struct GArgs {
  const u16* A; i64 lda, sAb;
  const u16* B; i64 ldb, sBb;
  void* C; i64 ldc, sCb;
  const float* p1; const float* p2;
  int K;
};

template <int MODE, int AM, int AN, int SWZ>
__global__ __launch_bounds__(256) void gemm_bt(GArgs g) {
  __shared__ __align__(16) u16 As[AM * 32 * 64];
  __shared__ __align__(16) u16 Bs[AN * 32 * 64];
  const int t = threadIdx.x, w = t >> 6, l = t & 63, quad = l >> 4, l15 = l & 15;
  const int wm = (w >> 1) * AM * 16, wn = (w & 1) * AN * 16;
  int bx = blockIdx.x, by = blockIdx.y, bz = blockIdx.z;
  if (SWZ == 1) {  // flat = bx + 8by + 256bz; pin same-by blocks to one XCD slot
    const int i = bx + (by << 3) + (bz << 8);
    const int slot = i & 7, jj = i >> 3;
    by = slot + ((jj & 3) << 3);
    const int j2 = jj >> 2;
    bx = j2 & 7;
    bz = j2 >> 3;
  }
  const u16* A = g.A + (i64)bz * g.sAb + (i64)bx * (AM * 32) * g.lda;
  const u16* Bp = g.B + (i64)bz * g.sBb + (i64)by * (AN * 32) * g.ldb;
  f32x4 acc[AM][AN] = {};
  gemm_core<AM, AN>(A, g.lda, Bp, g.ldb, g.K, As, Bs, acc);

  const int rowBase = bx * (AM * 32) + wm + quad * 4;
  const int colBase = by * (AN * 32) + wn + l15;
#pragma unroll
  for (int j = 0; j < AN; ++j) {
    const int col = colBase + j * 16;
    float cA = 0.f, cB = 0.f;
    if (MODE == 3) { cA = g.p1[col]; cB = g.p2[col]; }
#pragma unroll
    for (int i = 0; i < AM; ++i) {
#pragma unroll
      for (int r = 0; r < 4; ++r) {
        const int row = rowBase + i * 16 + r;
        float v = acc[i][j][r];
        if (MODE == 3) {  // BN+ReLU, bf16 out
          float x = v * cA + cB;
          ((u16*)g.C + (i64)bz * g.sCb)[(i64)row * g.ldc + col] = f2bf(x > 0.f ? x : 0.f);
        } else {  // MODE 4: fp32 out, row bias (W2 -> d_out)
          ((float*)g.C + (i64)bz * g.sCb)[(i64)row * g.ldc + col] = v + g.p1[row];
        }
      }
    }
  }
}

// ---------------- flash attention v8: register-P + double-buffered K/V (async prefetch) ----------------
// S^T = mfma(A=K, B=Q); P^T stays in C-regs == valid B-operand for O^T = mfma(A=V^T, P^T).
// Prefetch DMA issued AFTER the barrier -> the compiler's vmcnt(0)-before-barrier waits on a
// transfer that overlapped the whole compute phase, not a blocking fill.
__global__ __launch_bounds__(256) void flash_attn(const u16* __restrict__ Qh,
                                                  const u16* __restrict__ Kh,
                                                  const u16* __restrict__ Vt,
                                                  const u64* __restrict__ MW64,
                                                  u16* __restrict__ Opart,
                                                  float* __restrict__ Lp) {
  __shared__ __align__(16) u16 Ks0[64 * 64];
  __shared__ __align__(16) u16 Ks1[64 * 64];
  __shared__ __align__(16) u16 Vs0[64 * 64];
  __shared__ __align__(16) u16 Vs1[64 * 64];
  const int t = threadIdx.x, w = t >> 6, l = t & 63, l31 = l & 31, lh = l >> 5;
  // flat decode pinning all blocks of head h to one XCD slot (RR dispatch)
  const int flat = blockIdx.x;
  const int h = flat & 7;
  const int j = flat >> 3;
  const int nt = j & 15, zz = j >> 4;
  const int b = zz >> 2, sp = zz & 3;
  const int n = nt * 128 + w * 32 + l31;  // this lane's q-row
  const u16* Qb = Qh + ((i64)(b * HH + h) * NN + nt * 128 + w * 32) * 64;
  const u16* Kb = Kh + (i64)(b * HH + h) * NN * 64;
  const u16* Vb = Vt + (i64)(b * HH + h) * 64 * NN;
  const u64* mwp = MW64 + (i64)(b * NN + n) * 32;
  const bf16x8 ONE = ones8();
  // Q fragments (B-operand): lane q=l31, k = kc*16 + lh*8 + j
  bf16x8 qf[4];
#pragma unroll
  for (int kc = 0; kc < 4; ++kc)
    __builtin_memcpy(&qf[kc], Qb + (i64)l31 * 64 + kc * 16 + lh * 8, 16);

  f32x16 oacc0 = {}, oacc1 = {}, lacc = {};
  const int mt0 = sp * 8;

  auto stage = [&](u16* Kd, u16* Vd, int mt) {
#pragma unroll
    for (int j2 = 0; j2 < 2; ++j2) {
      int ch = j2 * 256 + t, r = ch >> 3, c = ch & 7;
      gload16(Kb + (i64)(mt * 64 + r) * 64 + ((c ^ (r & 7)) << 3), Kd + ch * 8);
      gload16(Vb + (i64)r * NN + mt * 64 + ((c ^ (r & 7)) << 3), Vd + ch * 8);
    }
  };
  auto compute = [&](const u16* Kc, const u16* Vc, int mt) {
    // S^T = K Q^T : C lane = q, regs = kv rows. Two kv tiles (0-31, 32-63).
    f32x16 s0 = {}, s1 = {};
#pragma unroll
    for (int kc = 0; kc < 4; ++kc) {
      const int sw = l31 & 7;
      bf16x8 k0 = ldfrag(&Kc[l31 * 64 + (((kc * 2 + lh) ^ sw) << 3)]);
      bf16x8 k1 = ldfrag(&Kc[(32 + l31) * 64 + (((kc * 2 + lh) ^ sw) << 3)]);
      s0 = mfma32(k0, qf[kc], s0);
      s1 = mfma32(k1, qf[kc], s1);
    }
    // p = exp2(s) masked; pack C-reg pairs in order -> B-operand frags pf[0..3]
    const u64 mrow = mwp[mt];
    u32 pw[16];
#pragma unroll
    for (int k = 0; k < 8; ++k) {
      const int kvb = ((2 * k) & 3) + 8 * ((2 * k) >> 2) + 4 * lh;
      u64 sh = mrow >> kvb;
      u32 mA = (((u32)sh & 1u) | (((u32)sh & 2u) << 15)) * 0xFFFFu;
      u32 shh = (u32)(sh >> 32);
      u32 mB = ((shh & 1u) | ((shh & 2u) << 15)) * 0xFFFFu;
      pw[k] = packbf(fexp2(s0[2 * k]), fexp2(s0[2 * k + 1])) & mA;
      pw[8 + k] = packbf(fexp2(s1[2 * k]), fexp2(s1[2 * k + 1])) & mB;
    }
    bf16x8 pf[4];
#pragma unroll
    for (int c = 0; c < 4; ++c) __builtin_memcpy(&pf[c], &pw[c * 4], 16);
#pragma unroll
    for (int c = 0; c < 4; ++c) lacc = mfma32(ONE, pf[c], lacc);  // l[q] per lane
    // O^T += V^T P^T : A = V^T frags with the sigma k-slot layout matching pf
#pragma unroll
    for (int c = 0; c < 4; ++c) {
      const int sw0 = l31 & 7;
      const u16* r0 = &Vc[l31 * 64];
      const u16* r1 = &Vc[(32 + l31) * 64];
      bf16x8 v0 = ldfrag2(r0 + (((2 * c) ^ sw0) << 3) + lh * 4,
                          r0 + (((2 * c + 1) ^ sw0) << 3) + lh * 4);
      bf16x8 v1 = ldfrag2(r1 + (((2 * c) ^ sw0) << 3) + lh * 4,
                          r1 + (((2 * c + 1) ^ sw0) << 3) + lh * 4);
      oacc0 = mfma32(v0, pf[c], oacc0);
      oacc1 = mfma32(v1, pf[c], oacc1);
    }
  };

  stage(Ks0, Vs0, mt0);
#pragma unroll
  for (int i = 0; i < 8; i += 2) {
    __syncthreads();                       // drains vmcnt -> buf0 ready
    stage(Ks1, Vs1, mt0 + i + 1);          // prefetch overlaps compute below
    compute(Ks0, Vs0, mt0 + i);
    __syncthreads();                       // drains vmcnt -> buf1 ready
    if (i + 2 < 8) stage(Ks0, Vs0, mt0 + i + 2);
    compute(Ks1, Vs1, mt0 + i + 1);
  }
  // epilogue: O^T partials -> Opart[sp][b][h][d][n] (lane=n, coalesced); Lp row sums
  u16* OpT = Opart + ((i64)((sp * BB + b) * HH + h) * 64) * NN;
#pragma unroll
  for (int r = 0; r < 16; ++r) {
    const int d0 = (r & 3) + 8 * (r >> 2) + 4 * lh;
    OpT[(i64)d0 * NN + n] = f2bf(oacc0[r]);
    OpT[(i64)(d0 + 32) * NN + n] = f2bf(oacc1[r]);
  }
  if (lh == 0) Lp[((i64)(sp * BB + b) * HH + h) * NN + n] = lacc[0];
}

// ---------------- combine: cat[n][h*64+d] = sum_sp O^T[d][n] / sum_sp l[n], LDS transpose ----------------
__global__ __launch_bounds__(256) void combine(const u16* __restrict__ Opart,
                                               const float* __restrict__ Lp,
                                               u16* __restrict__ cat) {
  __shared__ float lt[128 * 65];
  const int t = threadIdx.x;
  const int nt = blockIdx.x, bh = blockIdx.y;
  const int b = bh >> 3, h = bh & 7;
  const int n0 = nt * 128;
  const i64 sstride = (i64)BB * HH * 64 * NN;
  const u16* Ob = Opart + ((i64)(b * HH + h) * 64) * NN;
  // phase A: sum 4 sp partials, u32-pair loads, store [n][d] into LDS
#pragma unroll
  for (int i = 0; i < 16; ++i) {
    const int idx = i * 256 + t;  // [0, 4096): d x 64 n-pairs
    const int d = idx >> 6, np = idx & 63;
    float sa = 0.f, sb = 0.f;
#pragma unroll
    for (int s = 0; s < 4; ++s) {
      u32 v;
      __builtin_memcpy(&v, Ob + s * sstride + (i64)d * NN + n0 + 2 * np, 4);
      sa += bf2f32(v & 0xFFFFu);
      sb += bf2f32(v >> 16);
    }
    lt[(2 * np) * 65 + d] = sa;
    lt[(2 * np + 1) * 65 + d] = sb;
  }
  __syncthreads();
  // phase B: normalize rows and write cat (u32-packed, coalesced along d)
  u32* catw = (u32*)cat;
#pragma unroll
  for (int i = 0; i < 16; ++i) {
    const int idx = i * 256 + t;  // [0, 4096): n x 32 d-pairs
    const int nn = idx >> 5, dp = idx & 31;
    float lsum = 0.f;
#pragma unroll
    for (int s = 0; s < 4; ++s) lsum += Lp[((i64)(s * BB + b) * HH + h) * NN + n0 + nn];
    const float rl = __builtin_amdgcn_rcpf(lsum);
    u32 pv = packbf(lt[nn * 65 + 2 * dp] * rl, lt[nn * 65 + 2 * dp + 1] * rl);
    catw[((i64)b * NN + n0 + nn) * (D2 / 2) + h * 32 + dp] = pv;
  }
}

extern "C" void kernel_launch(void* const* d_in, const int* in_sizes, int n_in,
                              void* d_out, int out_size, void* d_ws, size_t ws_size,
                              hipStream_t stream) {
  (void)in_sizes; (void)n_in; (void)out_size; (void)ws_size;
  const float* iq    = (const float*)d_in[0];
  const float* kt    = (const float*)d_in[1];
  const float* vv    = (const float*)d_in[2];
  const int*   mask  = (const int*)d_in[3];
  const float* Wq    = (const float*)d_in[4];
  const float* bq    = (const float*)d_in[5];
  const float* Wk    = (const float*)d_in[6];
  const float* bk    = (const float*)d_in[7];
  const float* Wv    = (const float*)d_in[8];
  const float* bv    = (const float*)d_in[9];
  const float* Wm    = (const float*)d_in[10];
  const float* bm    = (const float*)d_in[11];
  const float* W1    = (const float*)d_in[12];
  const float* b1    = (const float*)d_in[13];
  const float* gamma_= (const float*)d_in[14];
  const float* beta_ = (const float*)d_in[15];
  const float* rmean = (const float*)d_in[16];
  const float* rvar  = (const float*)d_in[17];
  const float* W2    = (const float*)d_in[18];
  const float* b2    = (const float*)d_in[19];

  char* ws = (char*)d_ws;
  u16* cat = (u16*)(ws + OFF_CAT);
  u16* xkt = (u16*)(ws + OFF_XKT);
  u16* xvt = (u16*)(ws + OFF_XVT);
  u16* qh  = (u16*)(ws + OFF_QH);
  u16* kh  = (u16*)(ws + OFF_KH);
  u16* vt  = (u16*)(ws + OFF_VT);
  u16* ht  = (u16*)(ws + OFF_HT);
  u16* opart = (u16*)(ws + OFF_OP);
  float* lp  = (float*)(ws + OFF_LP);
  u16* wqp = (u16*)(ws + OFF_WQP);
  u16* wkp = (u16*)(ws + OFF_WKP);
  u16* wvp = (u16*)(ws + OFF_WVP);
  u16* wmt = (u16*)(ws + OFF_WMT);
  u16* w1a = (u16*)(ws + OFF_W1A);
  u16* w1c = (u16*)(ws + OFF_W1C);
  u16* w2b = (u16*)(ws + OFF_W2B);
  float* bqp = (float*)(ws + OFF_BQP);
  float* bkp = (float*)(ws + OFF_BKP);
  float* bvp = (float*)(ws + OFF_BVP);
  float* bna = (float*)(ws + OFF_BNA);
  float* bnc = (float*)(ws + OFF_BNC);
  u32* mw = (u32*)(ws + OFF_MSK);

  // 1. prep (weights/BN/mask) + input transpose, one launch
  prep_all<<<8977, 256, 0, stream>>>(Wq, Wk, Wv, Wm, W1, W2, bq, bk, bv, bm, b1, gamma_, beta_,
                                     rmean, rvar, mask, iq, kt, vv, wqp, wkp, wvp, wmt, w1a, w1c,
                                     w2b, bqp, bkp, bvp, bna, bnc, mw, cat, xkt, xvt);
  // 2. fused Q/K/V projections + Wc, 128x128 tiles, flat grid
  qkv_gemm<<<416, 256, 0, stream>>>(cat, xkt, xvt, wqp, wkp, wvp, w1a, wmt,
                                    bqp, bkp, bvp, qh, kh, vt, w1c);
  // 3. flash v8: register-P + double-buffered async K/V, KV-split-4, head-pinned XCDs
  flash_attn<<<1024, 256, 0, stream>>>(qh, kh, vt, (const u64*)mw, opart, lp);
  // 4. combine (transposing) into cat[:, 0:512]
  combine<<<dim3(16, 16), 256, 0, stream>>>(opart, lp, cat);
  // 5. W1' + BN + ReLU, batch-merged M=4096, 128x64 tiles
  GArgs wa{cat, D2, 0, w1c, D2, 0, ht, D2, 0, bna, bnc, D2};
  gemm_bt<3, 4, 2, 0><<<dim3(32, 16, 1), 256, 0, stream>>>(wa);
  // 6. W2 -> d_out (fp32), B-tiles XCD-pinned via SWZ
  GArgs w2a{w2b, D2, 0, ht, D2, (i64)NN * D2, d_out, NN, (i64)DD * NN, b2, nullptr, D2};
  gemm_bt<4, 2, 2, 1><<<dim3(8, 32, 2), 256, 0, stream>>>(w2a);
}

// Round 9
// 218.294 us; speedup vs baseline: 1.0183x; 1.0020x over previous
//
#include <hip/hip_runtime.h>

typedef unsigned short u16;
typedef unsigned int u32;
typedef unsigned long long u64;
typedef long long i64;
typedef __bf16 bf16x8 __attribute__((ext_vector_type(8)));
typedef u16 u16x8 __attribute__((ext_vector_type(8)));
typedef float f32x4 __attribute__((ext_vector_type(4)));
typedef float f32x16 __attribute__((ext_vector_type(16)));

#define DEV __device__ __forceinline__

// problem constants (fixed by harness)
constexpr int BB = 2, DD = 512, NN = 2048, HH = 8, DKc = 64, D2 = 1024;

// Q pre-scale: 1/sqrt(64) * log2(e)  (folded into Q so softmax uses native exp2)
constexpr float QSC = 0.125f * 1.44269504088896340736f;

// workspace byte offsets (16B aligned); NO aliasing
constexpr i64 MB = 1048576;
constexpr i64 OFF_CAT = 0;          // bf16 [B][N][D2]; [0:512)=attn (combine), [512:1024)=iq^T
constexpr i64 OFF_XKT = 8 * MB;     // bf16 [B][N][D] key_t^T
constexpr i64 OFF_XVT = 12 * MB;    // bf16 [B][N][D] value^T
constexpr i64 OFF_QH  = 16 * MB;    // bf16 [B][H][N][DK] (Q pre-scaled by QSC)
constexpr i64 OFF_KH  = 20 * MB;    // bf16 [B][H][N][DK]
constexpr i64 OFF_VT  = 24 * MB;    // bf16 [B][H][DK][N]  (natural m)
constexpr i64 OFF_HT  = 28 * MB;    // bf16 [B][N][D2]
constexpr i64 OFF_OP  = 36 * MB;    // bf16 [sp=4][B][H][DK][N] flash partials O^T (16 MB)
constexpr i64 OFF_LP  = 68 * MB;    // f32 [sp=4][B][H][N] flash partial row-sums
constexpr i64 OFF_WQP = 69 * MB;    // bf16 512x512 row-perm o'=h*64+dk
constexpr i64 OFF_WKP = 69 * MB + 524288;
constexpr i64 OFF_WVP = 69 * MB + 1048576;
constexpr i64 OFF_WMT = 69 * MB + 1572864;  // bf16 [c'=512][o=512] Wm^T col-permuted
constexpr i64 OFF_W1A = 71 * MB;    // bf16 [1024][512] W1 cols 0:512
constexpr i64 OFF_W1C = 72 * MB;    // bf16 [1024][1024]: cols 0:512 = W1a*Wm, cols 512: = W1b
constexpr i64 OFF_W2B = 74 * MB;    // bf16 512x1024
constexpr i64 OFF_BQP = 75 * MB;    // f32 512 (permuted)
constexpr i64 OFF_BKP = 75 * MB + 2048;
constexpr i64 OFF_BVP = 75 * MB + 4096;
constexpr i64 OFF_BNA = 75 * MB + 8192;   // f32 1024 BN scale
constexpr i64 OFF_BNC = 75 * MB + 12288;  // f32 1024 BN shift (incl b1 AND W1a*bm)
constexpr i64 OFF_MSK = 76 * MB;    // bit-packed mask u32 [B][N][64] (u64 rows per mt)

DEV u16 f2bf(float f) {  // round-to-nearest-even f32->bf16
  u32 u = __float_as_uint(f);
  u = u + 0x7FFFu + ((u >> 16) & 1u);
  return (u16)(u >> 16);
}

DEV float bf2f(u16 u) { return __uint_as_float(((u32)u) << 16); }
DEV float bf2f32(u32 u) { return __uint_as_float(u << 16); }

// pack two f32 -> two bf16 (truncation) in ONE v_perm_b32; lo -> low 16 bits
DEV u32 packbf(float lo, float hi) {
  return __builtin_amdgcn_perm(__float_as_uint(hi), __float_as_uint(lo), 0x07060302u);
}

DEV float fexp2(float x) {
#if __has_builtin(__builtin_amdgcn_exp2f)
  return __builtin_amdgcn_exp2f(x);
#else
  return exp2f(x);
#endif
}

DEV bf16x8 ldfrag(const u16* p) {  // 16B-aligned LDS fragment load
  bf16x8 v;
  __builtin_memcpy(&v, __builtin_assume_aligned(p, 16), 16);
  return v;
}

DEV bf16x8 ldfrag2(const u16* p0, const u16* p1) {  // two 8B LDS loads -> one frag
  bf16x8 v;
  __builtin_memcpy(&v, __builtin_assume_aligned(p0, 8), 8);
  __builtin_memcpy((char*)&v + 8, __builtin_assume_aligned(p1, 8), 8);
  return v;
}

DEV bf16x8 ones8() {  // bf16 1.0 x8
  u16x8 u = {0x3F80, 0x3F80, 0x3F80, 0x3F80, 0x3F80, 0x3F80, 0x3F80, 0x3F80};
  bf16x8 v;
  __builtin_memcpy(&v, &u, 16);
  return v;
}

// async global->LDS, 16B per lane; LDS dest = wave-uniform base + lane*16
DEV void gload16(const void* g, void* lds) {
  __builtin_amdgcn_global_load_lds((__attribute__((address_space(1))) void*)g,
                                   (__attribute__((address_space(3))) void*)lds, 16, 0, 0);
}

DEV f32x4 mfma16(bf16x8 a, bf16x8 b, f32x4 c) {
  return __builtin_amdgcn_mfma_f32_16x16x32_bf16(a, b, c, 0, 0, 0);
}

DEV f32x16 mfma32(bf16x8 a, bf16x8 b, f32x16 c) {
  return __builtin_amdgcn_mfma_f32_32x32x16_bf16(a, b, c, 0, 0, 0);
}

// ---------------- prep_all: weights, BN fold, mask pack, input transpose ----------------
__global__ __launch_bounds__(256) void prep_all(
    const float* __restrict__ Wq, const float* __restrict__ Wk, const float* __restrict__ Wv,
    const float* __restrict__ Wm, const float* __restrict__ W1, const float* __restrict__ W2,
    const float* __restrict__ bq, const float* __restrict__ bk, const float* __restrict__ bv,
    const float* __restrict__ bm, const float* __restrict__ b1, const float* __restrict__ gamma_,
    const float* __restrict__ beta_, const float* __restrict__ rmean,
    const float* __restrict__ rvar, const int* __restrict__ mask,
    const float* __restrict__ iq, const float* __restrict__ kt, const float* __restrict__ vv,
    u16* __restrict__ wqp, u16* __restrict__ wkp, u16* __restrict__ wvp, u16* __restrict__ wmt,
    u16* __restrict__ w1a, u16* __restrict__ w1c, u16* __restrict__ w2b,
    float* __restrict__ bqp, float* __restrict__ bkp, float* __restrict__ bvp,
    float* __restrict__ bna, float* __restrict__ bnc, u32* __restrict__ mw,
    u16* __restrict__ cat, u16* __restrict__ xkt, u16* __restrict__ xvt) {
  __shared__ float tile[32][33];
  const int blk = blockIdx.x, t = threadIdx.x;
  if (blk < 768) {  // Wq/Wk/Wv row-permute: dst row o'=h*64+dk <- src row dk*8+h
    const int which = blk >> 8, lb = blk & 255;
    const float* W = which == 0 ? Wq : (which == 1 ? Wk : Wv);
    u16* dst = which == 0 ? wqp : (which == 1 ? wkp : wvp);
    for (int e = lb * 256 + t; e < 262144; e += 65536) {
      int op = e >> 9, i = e & 511;
      int dk = op & 63, h = op >> 6;
      dst[e] = f2bf(W[(dk * 8 + h) * 512 + i]);
    }
  } else if (blk < 1024) {  // wmt[c'][o] = Wm[o][dk*8+h], c'=h*64+dk
    const int lb = blk - 768;
    for (int e = lb * 256 + t; e < 262144; e += 65536) {
      int cp = e >> 9, o = e & 511;
      int dk = cp & 63, h = cp >> 6;
      wmt[e] = f2bf(Wm[o * 512 + dk * 8 + h]);
    }
  } else if (blk < 1280) {  // w1a = W1[:, 0:512]
    const int lb = blk - 1024;
    for (int e = lb * 256 + t; e < 524288; e += 65536) {
      int row = e >> 9, o = e & 511;
      w1a[e] = f2bf(W1[(i64)row * 1024 + o]);
    }
  } else if (blk < 1536) {  // w1c[:, 512:1024] = W1[:, 512:1024]
    const int lb = blk - 1280;
    for (int e = lb * 256 + t; e < 524288; e += 65536) {
      int row = e >> 9, j = e & 511;
      w1c[(i64)row * 1024 + 512 + j] = f2bf(W1[(i64)row * 1024 + 512 + j]);
    }
  } else if (blk < 1792) {  // W2
    const int lb = blk - 1536;
    for (int e = lb * 256 + t; e < 524288; e += 65536) w2b[e] = f2bf(W2[e]);
  } else if (blk < 1808) {  // BN fold incl. s_e = sum_o W1a[e][o]*bm[o]
    __shared__ float sm[4][64];
    const int base = (blk - 1792) * 64;
    const int el = t & 63, oq = t >> 6;
    const float* wrow = W1 + (i64)(base + el) * 1024 + oq * 128;
    const float* bmq = bm + oq * 128;
    float s = 0.f;
#pragma unroll 8
    for (int j = 0; j < 128; j += 4) {
      float4 x = *(const float4*)(wrow + j);
      float4 y = *(const float4*)(bmq + j);
      s += x.x * y.x + x.y * y.y + x.z * y.z + x.w * y.w;
    }
    sm[oq][el] = s;
    __syncthreads();
    if (t < 64) {
      int e = base + t;
      float a = gamma_[e] * rsqrtf(rvar[e] + 1e-5f);
      bna[e] = a;
      bnc[e] = (b1[e] - rmean[e]) * a + beta_[e] + a * (sm[0][t] + sm[1][t] + sm[2][t] + sm[3][t]);
    }
  } else if (blk == 1808) {  // permuted projection biases
    for (int e = t; e < 512; e += 256) {
      int src = (e & 63) * 8 + (e >> 6);
      bqp[e] = bq[src]; bkp[e] = bk[src]; bvp[e] = bv[src];
    }
  } else if (blk < 2833) {  // mask pack: each lane packs its own 32 consecutive ints -> one u32
    const int tid = (blk - 1809) * 256 + t;  // [0, 262144)
    const i64 base = (i64)tid * 32;
    const int4* mp = (const int4*)(mask + base);
    u32 word = 0;
#pragma unroll
    for (int j = 0; j < 8; ++j) {
      int4 x = mp[j];
      u32 nib = (x.x != 0 ? 1u : 0u) | (x.y != 0 ? 2u : 0u) | (x.z != 0 ? 4u : 0u) |
                (x.w != 0 ? 8u : 0u);
      word |= nib << (j * 4);
    }
    mw[tid] = word;
  } else {  // transpose+convert: (B,D,N) f32 -> (B,N,D) bf16, packed u32 stores
    const int idx = blk - 2833;
    const int bx = idx & 63, by = (idx >> 6) & 15, bz = idx >> 10;
    const int tensor = bz >> 1, b = bz & 1;
    const float* src = (tensor == 0 ? iq : (tensor == 1 ? kt : vv)) + (i64)b * DD * NN;
    u16* dst; i64 ldd; int coff;
    if (tensor == 0)      { dst = cat + (i64)b * NN * D2; ldd = D2; coff = DD; }
    else if (tensor == 1) { dst = xkt + (i64)b * NN * DD; ldd = DD; coff = 0; }
    else                  { dst = xvt + (i64)b * NN * DD; ldd = DD; coff = 0; }
    const int x0 = bx * 32, y0 = by * 32;
    const int col = t & 31, rg = t >> 5;
#pragma unroll
    for (int i = 0; i < 4; ++i) {
      int row = rg + i * 8;
      tile[row][col] = src[(i64)(y0 + row) * NN + x0 + col];
    }
    __syncthreads();
    const int dp = t & 15, rbase = t >> 4;
    u32* dst32 = (u32*)dst;
    const i64 ldw = ldd >> 1;
    const int cw = (coff + y0) >> 1;
#pragma unroll
    for (int i = 0; i < 2; ++i) {
      int rr = rbase + i * 16;
      dst32[(i64)(x0 + rr) * ldw + cw + dp] = packbf(tile[2 * dp][rr], tile[2 * dp + 1][rr]);
    }
  }
}

// ---------------- shared GEMM core: (AM*32)x(AN*32) tile, BK=64, 4 waves 2x2 ----------------
template <int AM, int AN>
DEV void gemm_core(const u16* __restrict__ A, i64 lda, const u16* __restrict__ Bp, i64 ldb,
                   int K, u16* As, u16* Bs, f32x4 (&acc)[AM][AN]) {
  constexpr int BM = AM * 32, BN = AN * 32;
  const int t = threadIdx.x, w = t >> 6, l = t & 63, quad = l >> 4, l15 = l & 15;
  const int wm = (w >> 1) * AM * 16, wn = (w & 1) * AN * 16;
  for (int kk = 0; kk < K; kk += 64) {
    __syncthreads();
#pragma unroll
    for (int j = 0; j < BM / 32; ++j) {
      int ch = j * 256 + w * 64 + l, r = ch >> 3, c = ch & 7;
      gload16(A + (i64)r * lda + kk + ((c ^ (r & 7)) << 3), As + (j * 256 + w * 64) * 8);
    }
#pragma unroll
    for (int j = 0; j < BN / 32; ++j) {
      int ch = j * 256 + w * 64 + l, r = ch >> 3, c = ch & 7;
      gload16(Bp + (i64)r * ldb + kk + ((c ^ (r & 7)) << 3), Bs + (j * 256 + w * 64) * 8);
    }
    __syncthreads();
#pragma unroll
    for (int kc = 0; kc < 2; ++kc) {
      const int sw = ((kc * 4 + quad) ^ (l15 & 7)) << 3;
      bf16x8 af[AM], bfr[AN];
#pragma unroll
      for (int i = 0; i < AM; ++i) af[i] = ldfrag(&As[(wm + i * 16 + l15) * 64 + sw]);
#pragma unroll
      for (int j = 0; j < AN; ++j) bfr[j] = ldfrag(&Bs[(wn + j * 16 + l15) * 64 + sw]);
#pragma unroll
      for (int i = 0; i < AM; ++i)
#pragma unroll
        for (int j = 0; j < AN; ++j) acc[i][j] = mfma16(af[i], bfr[j], acc[i][j]);
    }
  }
}

// ---------------- fused Q/K/V projection + Wc weight-GEMM, 128x128 tiles, flat grid 416 ----------------
__global__ __launch_bounds__(256) void qkv_gemm(const u16* __restrict__ cat,
                                                const u16* __restrict__ xkt,
                                                const u16* __restrict__ xvt,
                                                const u16* __restrict__ wqp,
                                                const u16* __restrict__ wkp,
                                                const u16* __restrict__ wvp,
                                                const u16* __restrict__ w1a,
                                                const u16* __restrict__ wmt,
                                                const float* __restrict__ bqp,
                                                const float* __restrict__ bkp,
                                                const float* __restrict__ bvp,
                                                u16* __restrict__ qh, u16* __restrict__ kh,
                                                u16* __restrict__ vt, u16* __restrict__ w1c) {
  __shared__ __align__(16) u16 As[128 * 64];
  __shared__ __align__(16) u16 Bs[128 * 64];
  const int flat = blockIdx.x;
  const int t = threadIdx.x, w = t >> 6, l = t & 63, quad = l >> 4, l15 = l & 15;
  const int wm = (w >> 1) * 64, wn = (w & 1) * 64;
  int op, b = 0, mx, ny;
  if (flat < 256) {        // Q (0..127) / K (128..255): M=2048, N=512 -> 16x4 per b
    op = flat >> 7;
    b = (flat >> 6) & 1;
    const int r = flat & 63;
    mx = r >> 2; ny = r & 3;
  } else if (flat < 384) {  // V: M=512, N=2048 -> 4x16 per b
    op = 2;
    const int r = flat - 256;
    b = r >> 6;
    const int rr = r & 63;
    mx = rr >> 4; ny = rr & 15;
  } else {                  // Wc: M=1024, N=512 -> 8x4
    op = 3;
    const int r = flat - 384;
    mx = r >> 2; ny = r & 3;
  }
  const u16 *A, *Bp;
  i64 lda, ldb;
  if (op < 2) {
    A = (op == 0 ? cat + DD : xkt);
    lda = (op == 0 ? D2 : DD);
    A += (i64)b * NN * lda + (i64)mx * 128 * lda;
    Bp = (op == 0 ? wqp : wkp) + (i64)ny * 128 * DD;
    ldb = DD;
  } else if (op == 2) {
    A = wvp + (i64)mx * 128 * DD; lda = DD;
    Bp = xvt + (i64)b * NN * DD + (i64)ny * 128 * DD; ldb = DD;
  } else {
    A = w1a + (i64)mx * 128 * DD; lda = DD;
    Bp = wmt + (i64)ny * 128 * DD; ldb = DD;
  }
  f32x4 acc[4][4] = {};
  gemm_core<4, 4>(A, lda, Bp, ldb, DD, As, Bs, acc);

  const int rowBase = mx * 128 + wm + quad * 4;
  const int colBase = ny * 128 + wn + l15;
  if (op < 2) {  // head scatter: col=h*64+dk -> [b][h][n][dk]; Q scaled by QSC
    const float* bias = (op == 0 ? bqp : bkp);
    const float sc = (op == 0 ? QSC : 1.f);
    u16* dst = (op == 0 ? qh : kh) + (i64)b * HH * NN * DKc;
#pragma unroll
    for (int j = 0; j < 4; ++j) {
      const int col = colBase + j * 16;
      const float cA = bias[col];
#pragma unroll
      for (int i = 0; i < 4; ++i)
#pragma unroll
        for (int r = 0; r < 4; ++r) {
          const int row = rowBase + i * 16 + r;
          dst[(i64)(col >> 6) * (NN * 64) + (i64)row * 64 + (col & 63)] =
              f2bf((acc[i][j][r] + cA) * sc);
        }
    }
  } else if (op == 2) {  // V: row bias, store [b][o'][m] (natural m)
    u16* dst = vt + (i64)b * HH * DKc * NN;
#pragma unroll
    for (int j = 0; j < 4; ++j) {
      const int col = colBase + j * 16;
#pragma unroll
      for (int i = 0; i < 4; ++i)
#pragma unroll
        for (int r = 0; r < 4; ++r) {
          const int row = rowBase + i * 16 + r;
          dst[(i64)row * NN + col] = f2bf(acc[i][j][r] + bvp[row]);
        }
    }
  } else {  // Wc plain store -> w1c[:, 0:512]
#pragma unroll
    for (int j = 0; j < 4; ++j) {
      const int col = colBase + j * 16;
#pragma unroll
      for (int i = 0; i < 4; ++i)
#pragma unroll
        for (int r = 0; r < 4; ++r) {
          const int row = rowBase + i * 16 + r;
          w1c[(i64)row * D2 + col] = f2bf(acc[i][j][r]);
        }
    }
  }
}

// ---------------- generic gemm_bt: C[m][n] = A[m][:]·B[n][:] (+epilogue) ----------------
struct GArgs {
  const u16* A; i64 lda, sAb;
  const u16* B; i64 ldb, sBb;
  void* C; i64 ldc, sCb;
  const float* p1; const float* p2;
  int K;
};

template <int MODE, int AM, int AN, int SWZ>
__global__ __launch_bounds__(256) void gemm_bt(GArgs g) {
  __shared__ __align__(16) u16 As[AM * 32 * 64];
  __shared__ __align__(16) u16 Bs[AN * 32 * 64];
  const int t = threadIdx.x, w = t >> 6, l = t & 63, quad = l >> 4, l15 = l & 15;
  const int wm = (w >> 1) * AM * 16, wn = (w & 1) * AN * 16;
  int bx = blockIdx.x, by = blockIdx.y, bz = blockIdx.z;
  if (SWZ == 1) {  // flat = bx + 8by + 256bz; pin same-by blocks to one XCD slot
    const int i = bx + (by << 3) + (bz << 8);
    const int slot = i & 7, jj = i >> 3;
    by = slot + ((jj & 3) << 3);
    const int j2 = jj >> 2;
    bx = j2 & 7;
    bz = j2 >> 3;
  }
  const u16* A = g.A + (i64)bz * g.sAb + (i64)bx * (AM * 32) * g.lda;
  const u16* Bp = g.B + (i64)bz * g.sBb + (i64)by * (AN * 32) * g.ldb;
  f32x4 acc[AM][AN] = {};
  gemm_core<AM, AN>(A, g.lda, Bp, g.ldb, g.K, As, Bs, acc);

  const int rowBase = bx * (AM * 32) + wm + quad * 4;
  const int colBase = by * (AN * 32) + wn + l15;
#pragma unroll
  for (int j = 0; j < AN; ++j) {
    const int col = colBase + j * 16;
    float cA = 0.f, cB = 0.f;
    if (MODE == 3) { cA = g.p1[col]; cB = g.p2[col]; }
#pragma unroll
    for (int i = 0; i < AM; ++i) {
#pragma unroll
      for (int r = 0; r < 4; ++r) {
        const int row = rowBase + i * 16 + r;
        float v = acc[i][j][r];
        if (MODE == 3) {  // BN+ReLU, bf16 out
          float x = v * cA + cB;
          ((u16*)g.C + (i64)bz * g.sCb)[(i64)row * g.ldc + col] = f2bf(x > 0.f ? x : 0.f);
        } else {  // MODE 4: fp32 out, row bias (W2 -> d_out)
          ((float*)g.C + (i64)bz * g.sCb)[(i64)row * g.ldc + col] = v + g.p1[row];
        }
      }
    }
  }
}

// ---------------- flash attention v9: 512 threads, 256 q/block -> K/V DMA halved ----------------
// S^T = mfma(A=K, B=Q); P^T stays in C-regs == valid B-operand for O^T = mfma(A=V^T, P^T).
__global__ __launch_bounds__(512) void flash_attn(const u16* __restrict__ Qh,
                                                  const u16* __restrict__ Kh,
                                                  const u16* __restrict__ Vt,
                                                  const u64* __restrict__ MW64,
                                                  u16* __restrict__ Opart,
                                                  float* __restrict__ Lp) {
  __shared__ __align__(16) u16 Ks0[64 * 64];
  __shared__ __align__(16) u16 Ks1[64 * 64];
  __shared__ __align__(16) u16 Vs0[64 * 64];
  __shared__ __align__(16) u16 Vs1[64 * 64];
  const int t = threadIdx.x, w = t >> 6, l = t & 63, l31 = l & 31, lh = l >> 5;
  // flat decode pinning all blocks of head h to one XCD slot (RR dispatch, 512 blocks)
  const int flat = blockIdx.x;
  const int h = flat & 7;
  const int j = flat >> 3;
  const int nt = j & 7, zz = j >> 3;
  const int sp = zz & 3, b = zz >> 2;
  const int n = nt * 256 + w * 32 + l31;  // this lane's q-row (8 waves x 32 q = 256 q/block)
  const u16* Qb = Qh + ((i64)(b * HH + h) * NN + nt * 256 + w * 32) * 64;
  const u16* Kb = Kh + (i64)(b * HH + h) * NN * 64;
  const u16* Vb = Vt + (i64)(b * HH + h) * 64 * NN;
  const u64* mwp = MW64 + (i64)(b * NN + n) * 32;
  const bf16x8 ONE = ones8();
  // Q fragments (B-operand): lane q=l31, k = kc*16 + lh*8 + j
  bf16x8 qf[4];
#pragma unroll
  for (int kc = 0; kc < 4; ++kc)
    __builtin_memcpy(&qf[kc], Qb + (i64)l31 * 64 + kc * 16 + lh * 8, 16);

  f32x16 oacc0 = {}, oacc1 = {}, lacc = {};
  const int mt0 = sp * 8;

  // 512 threads cover a full 64x64 K tile + V tile in ONE gload16 pair per thread
  auto stage = [&](u16* Kd, u16* Vd, int mt) {
    const int r = t >> 3, c = t & 7;
    gload16(Kb + (i64)(mt * 64 + r) * 64 + ((c ^ (r & 7)) << 3), Kd + t * 8);
    gload16(Vb + (i64)r * NN + mt * 64 + ((c ^ (r & 7)) << 3), Vd + t * 8);
  };
  auto compute = [&](const u16* Kc, const u16* Vc, int mt) {
    // S^T = K Q^T : C lane = q, regs = kv rows. Two kv tiles (0-31, 32-63).
    f32x16 s0 = {}, s1 = {};
#pragma unroll
    for (int kc = 0; kc < 4; ++kc) {
      const int sw = l31 & 7;
      bf16x8 k0 = ldfrag(&Kc[l31 * 64 + (((kc * 2 + lh) ^ sw) << 3)]);
      bf16x8 k1 = ldfrag(&Kc[(32 + l31) * 64 + (((kc * 2 + lh) ^ sw) << 3)]);
      s0 = mfma32(k0, qf[kc], s0);
      s1 = mfma32(k1, qf[kc], s1);
    }
    // p = exp2(s) masked; pack C-reg pairs in order -> B-operand frags pf[0..3]
    const u64 mrow = mwp[mt];
    u32 pw[16];
#pragma unroll
    for (int k = 0; k < 8; ++k) {
      const int kvb = ((2 * k) & 3) + 8 * ((2 * k) >> 2) + 4 * lh;
      u64 sh = mrow >> kvb;
      u32 mA = (((u32)sh & 1u) | (((u32)sh & 2u) << 15)) * 0xFFFFu;
      u32 shh = (u32)(sh >> 32);
      u32 mB = ((shh & 1u) | ((shh & 2u) << 15)) * 0xFFFFu;
      pw[k] = packbf(fexp2(s0[2 * k]), fexp2(s0[2 * k + 1])) & mA;
      pw[8 + k] = packbf(fexp2(s1[2 * k]), fexp2(s1[2 * k + 1])) & mB;
    }
    bf16x8 pf[4];
#pragma unroll
    for (int c = 0; c < 4; ++c) __builtin_memcpy(&pf[c], &pw[c * 4], 16);
#pragma unroll
    for (int c = 0; c < 4; ++c) lacc = mfma32(ONE, pf[c], lacc);  // l[q] per lane
    // O^T += V^T P^T : A = V^T frags with the sigma k-slot layout matching pf
#pragma unroll
    for (int c = 0; c < 4; ++c) {
      const int sw0 = l31 & 7;
      const u16* r0 = &Vc[l31 * 64];
      const u16* r1 = &Vc[(32 + l31) * 64];
      bf16x8 v0 = ldfrag2(r0 + (((2 * c) ^ sw0) << 3) + lh * 4,
                          r0 + (((2 * c + 1) ^ sw0) << 3) + lh * 4);
      bf16x8 v1 = ldfrag2(r1 + (((2 * c) ^ sw0) << 3) + lh * 4,
                          r1 + (((2 * c + 1) ^ sw0) << 3) + lh * 4);
      oacc0 = mfma32(v0, pf[c], oacc0);
      oacc1 = mfma32(v1, pf[c], oacc1);
    }
  };

  stage(Ks0, Vs0, mt0);
#pragma unroll
  for (int i = 0; i < 8; i += 2) {
    __syncthreads();                       // drains vmcnt -> buf0 ready
    stage(Ks1, Vs1, mt0 + i + 1);          // prefetch overlaps compute below
    compute(Ks0, Vs0, mt0 + i);
    __syncthreads();                       // drains vmcnt -> buf1 ready
    if (i + 2 < 8) stage(Ks0, Vs0, mt0 + i + 2);
    compute(Ks1, Vs1, mt0 + i + 1);
  }
  // epilogue: O^T partials -> Opart[sp][b][h][d][n] (lane=n, coalesced); Lp row sums
  u16* OpT = Opart + ((i64)((sp * BB + b) * HH + h) * 64) * NN;
#pragma unroll
  for (int r = 0; r < 16; ++r) {
    const int d0 = (r & 3) + 8 * (r >> 2) + 4 * lh;
    OpT[(i64)d0 * NN + n] = f2bf(oacc0[r]);
    OpT[(i64)(d0 + 32) * NN + n] = f2bf(oacc1[r]);
  }
  if (lh == 0) Lp[((i64)(sp * BB + b) * HH + h) * NN + n] = lacc[0];
}

// ---------------- combine: cat[n][h*64+d] = sum_sp O^T[d][n] / sum_sp l[n], LDS transpose ----------------
__global__ __launch_bounds__(256) void combine(const u16* __restrict__ Opart,
                                               const float* __restrict__ Lp,
                                               u16* __restrict__ cat) {
  __shared__ float lt[128 * 65];
  const int t = threadIdx.x;
  const int nt = blockIdx.x, bh = blockIdx.y;
  const int b = bh >> 3, h = bh & 7;
  const int n0 = nt * 128;
  const i64 sstride = (i64)BB * HH * 64 * NN;
  const u16* Ob = Opart + ((i64)(b * HH + h) * 64) * NN;
  // phase A: sum 4 sp partials, u32-pair loads, store [n][d] into LDS
#pragma unroll
  for (int i = 0; i < 16; ++i) {
    const int idx = i * 256 + t;  // [0, 4096): d x 64 n-pairs
    const int d = idx >> 6, np = idx & 63;
    float sa = 0.f, sb = 0.f;
#pragma unroll
    for (int s = 0; s < 4; ++s) {
      u32 v;
      __builtin_memcpy(&v, Ob + s * sstride + (i64)d * NN + n0 + 2 * np, 4);
      sa += bf2f32(v & 0xFFFFu);
      sb += bf2f32(v >> 16);
    }
    lt[(2 * np) * 65 + d] = sa;
    lt[(2 * np + 1) * 65 + d] = sb;
  }
  __syncthreads();
  // phase B: normalize rows and write cat (u32-packed, coalesced along d)
  u32* catw = (u32*)cat;
#pragma unroll
  for (int i = 0; i < 16; ++i) {
    const int idx = i * 256 + t;  // [0, 4096): n x 32 d-pairs
    const int nn = idx >> 5, dp = idx & 31;
    float lsum = 0.f;
#pragma unroll
    for (int s = 0; s < 4; ++s) lsum += Lp[((i64)(s * BB + b) * HH + h) * NN + n0 + nn];
    const float rl = __builtin_amdgcn_rcpf(lsum);
    u32 pv = packbf(lt[nn * 65 + 2 * dp] * rl, lt[nn * 65 + 2 * dp + 1] * rl);
    catw[((i64)b * NN + n0 + nn) * (D2 / 2) + h * 32 + dp] = pv;
  }
}

extern "C" void kernel_launch(void* const* d_in, const int* in_sizes, int n_in,
                              void* d_out, int out_size, void* d_ws, size_t ws_size,
                              hipStream_t stream) {
  (void)in_sizes; (void)n_in; (void)out_size; (void)ws_size;
  const float* iq    = (const float*)d_in[0];
  const float* kt    = (const float*)d_in[1];
  const float* vv    = (const float*)d_in[2];
  const int*   mask  = (const int*)d_in[3];
  const float* Wq    = (const float*)d_in[4];
  const float* bq    = (const float*)d_in[5];
  const float* Wk    = (const float*)d_in[6];
  const float* bk    = (const float*)d_in[7];
  const float* Wv    = (const float*)d_in[8];
  const float* bv    = (const float*)d_in[9];
  const float* Wm    = (const float*)d_in[10];
  const float* bm    = (const float*)d_in[11];
  const float* W1    = (const float*)d_in[12];
  const float* b1    = (const float*)d_in[13];
  const float* gamma_= (const float*)d_in[14];
  const float* beta_ = (const float*)d_in[15];
  const float* rmean = (const float*)d_in[16];
  const float* rvar  = (const float*)d_in[17];
  const float* W2    = (const float*)d_in[18];
  const float* b2    = (const float*)d_in[19];

  char* ws = (char*)d_ws;
  u16* cat = (u16*)(ws + OFF_CAT);
  u16* xkt = (u16*)(ws + OFF_XKT);
  u16* xvt = (u16*)(ws + OFF_XVT);
  u16* qh  = (u16*)(ws + OFF_QH);
  u16* kh  = (u16*)(ws + OFF_KH);
  u16* vt  = (u16*)(ws + OFF_VT);
  u16* ht  = (u16*)(ws + OFF_HT);
  u16* opart = (u16*)(ws + OFF_OP);
  float* lp  = (float*)(ws + OFF_LP);
  u16* wqp = (u16*)(ws + OFF_WQP);
  u16* wkp = (u16*)(ws + OFF_WKP);
  u16* wvp = (u16*)(ws + OFF_WVP);
  u16* wmt = (u16*)(ws + OFF_WMT);
  u16* w1a = (u16*)(ws + OFF_W1A);
  u16* w1c = (u16*)(ws + OFF_W1C);
  u16* w2b = (u16*)(ws + OFF_W2B);
  float* bqp = (float*)(ws + OFF_BQP);
  float* bkp = (float*)(ws + OFF_BKP);
  float* bvp = (float*)(ws + OFF_BVP);
  float* bna = (float*)(ws + OFF_BNA);
  float* bnc = (float*)(ws + OFF_BNC);
  u32* mw = (u32*)(ws + OFF_MSK);

  // 1. prep (weights/BN/mask) + input transpose, one launch
  prep_all<<<8977, 256, 0, stream>>>(Wq, Wk, Wv, Wm, W1, W2, bq, bk, bv, bm, b1, gamma_, beta_,
                                     rmean, rvar, mask, iq, kt, vv, wqp, wkp, wvp, wmt, w1a, w1c,
                                     w2b, bqp, bkp, bvp, bna, bnc, mw, cat, xkt, xvt);
  // 2. fused Q/K/V projections + Wc, 128x128 tiles, flat grid
  qkv_gemm<<<416, 256, 0, stream>>>(cat, xkt, xvt, wqp, wkp, wvp, w1a, wmt,
                                    bqp, bkp, bvp, qh, kh, vt, w1c);
  // 3. flash v9: 512 threads / 256 q per block (K/V DMA halved), dbuf, head-pinned XCDs
  flash_attn<<<512, 512, 0, stream>>>(qh, kh, vt, (const u64*)mw, opart, lp);
  // 4. combine (transposing) into cat[:, 0:512]
  combine<<<dim3(16, 16), 256, 0, stream>>>(opart, lp, cat);
  // 5. W1' + BN + ReLU, batch-merged M=4096, 128x64 tiles
  GArgs wa{cat, D2, 0, w1c, D2, 0, ht, D2, 0, bna, bnc, D2};
  gemm_bt<3, 4, 2, 0><<<dim3(32, 16, 1), 256, 0, stream>>>(wa);
  // 6. W2 -> d_out (fp32), B-tiles XCD-pinned via SWZ
  GArgs w2a{w2b, D2, 0, ht, D2, (i64)NN * D2, d_out, NN, (i64)DD * NN, b2, nullptr, D2};
  gemm_bt<4, 2, 2, 1><<<dim3(8, 32, 2), 256, 0, stream>>>(w2a);
}